// Round 4
// baseline (7507.080 us; speedup 1.0000x reference)
//
#include <hip/hip_runtime.h>
#include <hip/hip_bf16.h>

// Problem constants (fixed shapes)
#define BATCH 2
#define SEQ   2048
#define EMB   1024
#define DATTN 1024
#define NH    16
#define HD    64
#define MM    (BATCH*SEQ)        // 4096 rows
#define SCALE 0.03125f           // 1/sqrt(1024)

// ---------------- GEMM: C = A @ W^T, A fp32 [M,K], W fp32 [N,K] ----------------
// Stores fp32 into head layout [B, H, S, HD]:  (((b*NH+h)*SEQ)+s)*HD + d
#define BM 64
#define BN 64
#define BK 16

__global__ void gemm_proj_kernel(const float* __restrict__ A,
                                 const float* __restrict__ W,
                                 float* __restrict__ Chead)
{
    const int K = EMB;
    __shared__ float As[BM][BK + 1];
    __shared__ float Bs[BN][BK + 1];
    const int tid = threadIdx.x;
    const int tx = tid & 15, ty = tid >> 4;
    const int m0 = blockIdx.x * BM;
    const int n0 = blockIdx.y * BN;

    float acc[4][4] = {};

    for (int kt = 0; kt < K; kt += BK) {
        int idx = tid * 4;
        int row = idx >> 4;      // /16
        int col = idx & 15;      // 0,4,8,12
        float4 av = *(const float4*)(A + (long)(m0 + row) * K + kt + col);
        float4 wv = *(const float4*)(W + (long)(n0 + row) * K + kt + col);
        As[row][col + 0] = av.x; As[row][col + 1] = av.y;
        As[row][col + 2] = av.z; As[row][col + 3] = av.w;
        Bs[row][col + 0] = wv.x; Bs[row][col + 1] = wv.y;
        Bs[row][col + 2] = wv.z; Bs[row][col + 3] = wv.w;
        __syncthreads();

        #pragma unroll
        for (int kk = 0; kk < BK; ++kk) {
            float a[4], b[4];
            #pragma unroll
            for (int r = 0; r < 4; ++r) a[r] = As[ty * 4 + r][kk];
            #pragma unroll
            for (int c = 0; c < 4; ++c) b[c] = Bs[tx * 4 + c][kk];
            #pragma unroll
            for (int r = 0; r < 4; ++r)
                #pragma unroll
                for (int c = 0; c < 4; ++c)
                    acc[r][c] += a[r] * b[c];
        }
        __syncthreads();
    }

    #pragma unroll
    for (int r = 0; r < 4; ++r) {
        const int m = m0 + ty * 4 + r;
        const int b = m >> 11;          // /SEQ
        const int s = m & (SEQ - 1);
        #pragma unroll
        for (int c = 0; c < 4; ++c) {
            const int n = n0 + tx * 4 + c;
            const int h = n >> 6;       // /HD
            const int d = n & (HD - 1);
            Chead[((((long)(b * NH + h)) * SEQ + s) << 6) + d] = acc[r][c];
        }
    }
}

// ---------------- GEMM: out = ctx @ Wo^T, ctx fp32 [M,K], Wo fp32 [N,K], out fp32 ----------------
__global__ void gemm_out_kernel(const float* __restrict__ A,
                                const float* __restrict__ W,
                                float* __restrict__ C)
{
    const int K = DATTN, N = EMB;
    __shared__ float As[BM][BK + 1];
    __shared__ float Bs[BN][BK + 1];
    const int tid = threadIdx.x;
    const int tx = tid & 15, ty = tid >> 4;
    const int m0 = blockIdx.x * BM;
    const int n0 = blockIdx.y * BN;

    float acc[4][4] = {};

    for (int kt = 0; kt < K; kt += BK) {
        int idx = tid * 4;
        int row = idx >> 4;
        int col = idx & 15;
        float4 av = *(const float4*)(A + (long)(m0 + row) * K + kt + col);
        float4 wv = *(const float4*)(W + (long)(n0 + row) * K + kt + col);
        As[row][col + 0] = av.x; As[row][col + 1] = av.y;
        As[row][col + 2] = av.z; As[row][col + 3] = av.w;
        Bs[row][col + 0] = wv.x; Bs[row][col + 1] = wv.y;
        Bs[row][col + 2] = wv.z; Bs[row][col + 3] = wv.w;
        __syncthreads();

        #pragma unroll
        for (int kk = 0; kk < BK; ++kk) {
            float a[4], b[4];
            #pragma unroll
            for (int r = 0; r < 4; ++r) a[r] = As[ty * 4 + r][kk];
            #pragma unroll
            for (int c = 0; c < 4; ++c) b[c] = Bs[tx * 4 + c][kk];
            #pragma unroll
            for (int r = 0; r < 4; ++r)
                #pragma unroll
                for (int c = 0; c < 4; ++c)
                    acc[r][c] += a[r] * b[c];
        }
        __syncthreads();
    }

    #pragma unroll
    for (int r = 0; r < 4; ++r) {
        const int m = m0 + ty * 4 + r;
        #pragma unroll
        for (int c = 0; c < 4; ++c) {
            const int n = n0 + tx * 4 + c;
            C[(long)m * N + n] = acc[r][c];
        }
    }
}

// ---------------- RoPE (in-place on head-layout tensor [B,H,S,HD]) ----------------
__global__ void rope_kernel(float* __restrict__ X)
{
    const int t = blockIdx.x * blockDim.x + threadIdx.x;
    if (t >= BATCH * NH * SEQ * (HD / 2)) return;
    const int p  = t & 31;               // pair index in head dim
    const int s  = (t >> 5) & (SEQ - 1);
    const int bh = t >> 16;              // b*NH + h
    const long base = (((long)bh * SEQ + s) << 6) + p * 2;
    const float inv_freq = powf(10000.0f, -(float)(2 * p) / 64.0f);
    const float ang = (float)s * inv_freq;
    float c, sn;
    __sincosf(ang, &sn, &c);
    const float x0 = X[base], x1 = X[base + 1];
    X[base]     = x0 * c - x1 * sn;
    X[base + 1] = x0 * sn + x1 * c;
}

// ---------------- Flash attention: block = (b, h, 128-query tile) ----------------
// 256 threads: tid = 4*qpair + p.  Thread owns query rows (2*qpair, 2*qpair+1)
// and head-dim slice [16p, 16p+16).  K/V staged in LDS in 64-key tiles.
// Scores processed 8 keys at a time (register budget: no spills, no launch_bounds cap).
// mask: allowed j < i (strict), except i==0 -> only j==0
#define TQ 128
#define TJ 64
#define MINIT -1.0e30f

__global__ void flash_attn_kernel(const float* __restrict__ Qh,
                                  const float* __restrict__ Kh,
                                  const float* __restrict__ Vh,
                                  float* __restrict__ ctx)
{
    const int nt = SEQ / TQ;                 // 16 query tiles
    const int t  = nt - 1 - blockIdx.x;      // heavy tiles dispatched first
    const int h  = blockIdx.y, b = blockIdx.z;
    const int tid = threadIdx.x;
    const int p  = tid & 3;
    const int qp = tid >> 2;                 // 0..63
    const int r0 = t * TQ;
    const int i0 = r0 + qp * 2;
    const int i1 = i0 + 1;
    const int dbase = p * 16;

    __shared__ __align__(16) float sk[TJ][HD];
    __shared__ __align__(16) float sv[TJ][HD];

    const long base = ((long)(b * NH + h)) * SEQ * HD;

    // Q fragments in registers (pre-scaled): 2 rows x 16 dims
    float q0r[16], q1r[16];
    {
        const float4* qa = (const float4*)(Qh + base + (long)i0 * HD + dbase);
        const float4* qb = (const float4*)(Qh + base + (long)i1 * HD + dbase);
        #pragma unroll
        for (int u = 0; u < 4; ++u) {
            float4 va = qa[u], vb = qb[u];
            q0r[4*u+0] = va.x * SCALE; q0r[4*u+1] = va.y * SCALE;
            q0r[4*u+2] = va.z * SCALE; q0r[4*u+3] = va.w * SCALE;
            q1r[4*u+0] = vb.x * SCALE; q1r[4*u+1] = vb.y * SCALE;
            q1r[4*u+2] = vb.z * SCALE; q1r[4*u+3] = vb.w * SCALE;
        }
    }

    float acc0[16], acc1[16];
    #pragma unroll
    for (int d = 0; d < 16; ++d) { acc0[d] = 0.f; acc1[d] = 0.f; }
    float m0 = MINIT, m1 = MINIT, l0 = 0.f, l1 = 0.f;

    const int njt = (r0 + TQ - 2) / TJ + 1;   // = 2t+2 key tiles

    for (int jt = 0; jt < njt; ++jt) {
        const int jbase = jt * TJ;

        __syncthreads();   // protect previous-iteration LDS reads
        #pragma unroll
        for (int u = 0; u < 4; ++u) {
            int idx = u * 1024 + tid * 4;
            int r = idx >> 6, c = idx & 63;
            *(float4*)&sk[r][c] = *(const float4*)(Kh + base + (long)(jbase + r) * HD + c);
            *(float4*)&sv[r][c] = *(const float4*)(Vh + base + (long)(jbase + r) * HD + c);
        }
        __syncthreads();

        const bool masked_tile = (jbase + TJ > r0);

        #pragma unroll
        for (int c8 = 0; c8 < 8; ++c8) {
            float s0[8], s1[8];
            // partial dots over this thread's 16 dims
            #pragma unroll
            for (int kk = 0; kk < 8; ++kk) {
                const int jj = c8 * 8 + kk;
                const float4* kp = (const float4*)&sk[jj][dbase];
                float d0 = 0.f, d1 = 0.f;
                #pragma unroll
                for (int u = 0; u < 4; ++u) {
                    float4 kv = kp[u];
                    d0 += kv.x * q0r[4*u+0] + kv.y * q0r[4*u+1]
                        + kv.z * q0r[4*u+2] + kv.w * q0r[4*u+3];
                    d1 += kv.x * q1r[4*u+0] + kv.y * q1r[4*u+1]
                        + kv.z * q1r[4*u+2] + kv.w * q1r[4*u+3];
                }
                s0[kk] = d0; s1[kk] = d1;
            }
            // reduce partials across the 4 p-lanes (low 2 bits of lane id)
            #pragma unroll
            for (int kk = 0; kk < 8; ++kk) {
                s0[kk] += __shfl_xor(s0[kk], 1, 64);
                s0[kk] += __shfl_xor(s0[kk], 2, 64);
                s1[kk] += __shfl_xor(s1[kk], 1, 64);
                s1[kk] += __shfl_xor(s1[kk], 2, 64);
            }
            // causal mask (masked score -> -inf; m stays finite so no NaN)
            if (masked_tile) {
                #pragma unroll
                for (int kk = 0; kk < 8; ++kk) {
                    const int j = jbase + c8 * 8 + kk;
                    const bool a0 = (j < i0) || (i0 == 0 && j == 0);
                    const bool a1 = (j < i1);
                    if (!a0) s0[kk] = -INFINITY;
                    if (!a1) s1[kk] = -INFINITY;
                }
            }
            // online softmax update (branch-free: m finite always)
            float mx0 = s0[0], mx1 = s1[0];
            #pragma unroll
            for (int kk = 1; kk < 8; ++kk) { mx0 = fmaxf(mx0, s0[kk]); mx1 = fmaxf(mx1, s1[kk]); }
            const float mn0 = fmaxf(m0, mx0), mn1 = fmaxf(m1, mx1);
            const float a0 = __expf(m0 - mn0);
            const float a1 = __expf(m1 - mn1);
            float ss0 = 0.f, ss1 = 0.f;
            #pragma unroll
            for (int kk = 0; kk < 8; ++kk) {
                const float e0 = __expf(s0[kk] - mn0);
                const float e1 = __expf(s1[kk] - mn1);
                s0[kk] = e0; s1[kk] = e1;
                ss0 += e0; ss1 += e1;
            }
            l0 = l0 * a0 + ss0;
            l1 = l1 * a1 + ss1;
            m0 = mn0; m1 = mn1;
            #pragma unroll
            for (int d = 0; d < 16; ++d) { acc0[d] *= a0; acc1[d] *= a1; }
            // PV accumulate (V read shared by both query rows)
            #pragma unroll
            for (int kk = 0; kk < 8; ++kk) {
                const int jj = c8 * 8 + kk;
                const float4* vp = (const float4*)&sv[jj][dbase];
                const float e0 = s0[kk], e1 = s1[kk];
                #pragma unroll
                for (int u = 0; u < 4; ++u) {
                    float4 vv = vp[u];
                    acc0[4*u+0] += e0 * vv.x; acc0[4*u+1] += e0 * vv.y;
                    acc0[4*u+2] += e0 * vv.z; acc0[4*u+3] += e0 * vv.w;
                    acc1[4*u+0] += e1 * vv.x; acc1[4*u+1] += e1 * vv.y;
                    acc1[4*u+2] += e1 * vv.z; acc1[4*u+3] += e1 * vv.w;
                }
            }
        }
    }

    // epilogue: ctx layout [B, S, DATTN]
    const float inv0 = 1.f / l0, inv1 = 1.f / l1;
    float* o0 = ctx + ((long)(b * SEQ + i0)) * DATTN + h * HD + dbase;
    float* o1 = ctx + ((long)(b * SEQ + i1)) * DATTN + h * HD + dbase;
    #pragma unroll
    for (int u = 0; u < 4; ++u) {
        float4 w0, w1;
        w0.x = acc0[4*u+0] * inv0; w0.y = acc0[4*u+1] * inv0;
        w0.z = acc0[4*u+2] * inv0; w0.w = acc0[4*u+3] * inv0;
        w1.x = acc1[4*u+0] * inv1; w1.y = acc1[4*u+1] * inv1;
        w1.z = acc1[4*u+2] * inv1; w1.w = acc1[4*u+3] * inv1;
        *(float4*)(o0 + 4*u) = w0;
        *(float4*)(o1 + 4*u) = w1;
    }
}

extern "C" void kernel_launch(void* const* d_in, const int* in_sizes, int n_in,
                              void* d_out, int out_size, void* d_ws, size_t ws_size,
                              hipStream_t stream) {
    const float* q  = (const float*)d_in[0];
    const float* k  = (const float*)d_in[1];
    const float* v  = (const float*)d_in[2];
    const float* Wq = (const float*)d_in[3];
    const float* Wk = (const float*)d_in[4];
    const float* Wv = (const float*)d_in[5];
    const float* Wo = (const float*)d_in[6];
    float* out = (float*)d_out;

    // workspace layout (fp32): Qh | Kh | Vh | ctx  — 4 x 16 MB = 64 MB
    const long TSZ = (long)BATCH * NH * SEQ * HD;   // 4,194,304
    float* Qh  = (float*)d_ws;
    float* Kh  = Qh + TSZ;
    float* Vh  = Kh + TSZ;
    float* ctx = Vh + TSZ;

    dim3 gemm_grid(MM / BM, DATTN / BN);   // (64, 16)
    gemm_proj_kernel<<<gemm_grid, 256, 0, stream>>>(q, Wq, Qh);
    gemm_proj_kernel<<<gemm_grid, 256, 0, stream>>>(k, Wk, Kh);
    gemm_proj_kernel<<<gemm_grid, 256, 0, stream>>>(v, Wv, Vh);

    const int npairs = BATCH * NH * SEQ * (HD / 2);  // 2,097,152
    rope_kernel<<<(npairs + 255) / 256, 256, 0, stream>>>(Qh);
    rope_kernel<<<(npairs + 255) / 256, 256, 0, stream>>>(Kh);

    flash_attn_kernel<<<dim3(SEQ / TQ, NH, BATCH), 256, 0, stream>>>(Qh, Kh, Vh, ctx);

    gemm_out_kernel<<<gemm_grid, 256, 0, stream>>>(ctx, Wo, out);
}

// Round 5
// 5871.029 us; speedup vs baseline: 1.2787x; 1.2787x over previous
//
#include <hip/hip_runtime.h>
#include <hip/hip_bf16.h>

// Problem constants (fixed shapes)
#define BATCH 2
#define SEQ   2048
#define EMB   1024
#define DATTN 1024
#define NH    16
#define HD    64
#define MM    (BATCH*SEQ)        // 4096 rows
#define SCALE 0.03125f           // 1/sqrt(1024)

// ---------------- GEMM: C = A @ W^T, A fp32 [M,K], W fp32 [N,K] ----------------
// Stores fp32 into head layout [B, H, S, HD]:  (((b*NH+h)*SEQ)+s)*HD + d
#define BM 64
#define BN 64
#define BK 16

__global__ void gemm_proj_kernel(const float* __restrict__ A,
                                 const float* __restrict__ W,
                                 float* __restrict__ Chead)
{
    const int K = EMB;
    __shared__ float As[BM][BK + 1];
    __shared__ float Bs[BN][BK + 1];
    const int tid = threadIdx.x;
    const int tx = tid & 15, ty = tid >> 4;
    const int m0 = blockIdx.x * BM;
    const int n0 = blockIdx.y * BN;

    float acc[4][4] = {};

    for (int kt = 0; kt < K; kt += BK) {
        int idx = tid * 4;
        int row = idx >> 4;      // /16
        int col = idx & 15;      // 0,4,8,12
        float4 av = *(const float4*)(A + (long)(m0 + row) * K + kt + col);
        float4 wv = *(const float4*)(W + (long)(n0 + row) * K + kt + col);
        As[row][col + 0] = av.x; As[row][col + 1] = av.y;
        As[row][col + 2] = av.z; As[row][col + 3] = av.w;
        Bs[row][col + 0] = wv.x; Bs[row][col + 1] = wv.y;
        Bs[row][col + 2] = wv.z; Bs[row][col + 3] = wv.w;
        __syncthreads();

        #pragma unroll
        for (int kk = 0; kk < BK; ++kk) {
            float a[4], b[4];
            #pragma unroll
            for (int r = 0; r < 4; ++r) a[r] = As[ty * 4 + r][kk];
            #pragma unroll
            for (int c = 0; c < 4; ++c) b[c] = Bs[tx * 4 + c][kk];
            #pragma unroll
            for (int r = 0; r < 4; ++r)
                #pragma unroll
                for (int c = 0; c < 4; ++c)
                    acc[r][c] += a[r] * b[c];
        }
        __syncthreads();
    }

    #pragma unroll
    for (int r = 0; r < 4; ++r) {
        const int m = m0 + ty * 4 + r;
        const int b = m >> 11;          // /SEQ
        const int s = m & (SEQ - 1);
        #pragma unroll
        for (int c = 0; c < 4; ++c) {
            const int n = n0 + tx * 4 + c;
            const int h = n >> 6;       // /HD
            const int d = n & (HD - 1);
            Chead[((((long)(b * NH + h)) * SEQ + s) << 6) + d] = acc[r][c];
        }
    }
}

// ---------------- GEMM: out = ctx @ Wo^T, ctx fp32 [M,K], Wo fp32 [N,K], out fp32 ----------------
__global__ void gemm_out_kernel(const float* __restrict__ A,
                                const float* __restrict__ W,
                                float* __restrict__ C)
{
    const int K = DATTN, N = EMB;
    __shared__ float As[BM][BK + 1];
    __shared__ float Bs[BN][BK + 1];
    const int tid = threadIdx.x;
    const int tx = tid & 15, ty = tid >> 4;
    const int m0 = blockIdx.x * BM;
    const int n0 = blockIdx.y * BN;

    float acc[4][4] = {};

    for (int kt = 0; kt < K; kt += BK) {
        int idx = tid * 4;
        int row = idx >> 4;
        int col = idx & 15;
        float4 av = *(const float4*)(A + (long)(m0 + row) * K + kt + col);
        float4 wv = *(const float4*)(W + (long)(n0 + row) * K + kt + col);
        As[row][col + 0] = av.x; As[row][col + 1] = av.y;
        As[row][col + 2] = av.z; As[row][col + 3] = av.w;
        Bs[row][col + 0] = wv.x; Bs[row][col + 1] = wv.y;
        Bs[row][col + 2] = wv.z; Bs[row][col + 3] = wv.w;
        __syncthreads();

        #pragma unroll
        for (int kk = 0; kk < BK; ++kk) {
            float a[4], b[4];
            #pragma unroll
            for (int r = 0; r < 4; ++r) a[r] = As[ty * 4 + r][kk];
            #pragma unroll
            for (int c = 0; c < 4; ++c) b[c] = Bs[tx * 4 + c][kk];
            #pragma unroll
            for (int r = 0; r < 4; ++r)
                #pragma unroll
                for (int c = 0; c < 4; ++c)
                    acc[r][c] += a[r] * b[c];
        }
        __syncthreads();
    }

    #pragma unroll
    for (int r = 0; r < 4; ++r) {
        const int m = m0 + ty * 4 + r;
        #pragma unroll
        for (int c = 0; c < 4; ++c) {
            const int n = n0 + tx * 4 + c;
            C[(long)m * N + n] = acc[r][c];
        }
    }
}

// ---------------- RoPE (in-place on head-layout tensor [B,H,S,HD]) ----------------
__global__ void rope_kernel(float* __restrict__ X)
{
    const int t = blockIdx.x * blockDim.x + threadIdx.x;
    if (t >= BATCH * NH * SEQ * (HD / 2)) return;
    const int p  = t & 31;               // pair index in head dim
    const int s  = (t >> 5) & (SEQ - 1);
    const int bh = t >> 16;              // b*NH + h
    const long base = (((long)bh * SEQ + s) << 6) + p * 2;
    const float inv_freq = powf(10000.0f, -(float)(2 * p) / 64.0f);
    const float ang = (float)s * inv_freq;
    float c, sn;
    __sincosf(ang, &sn, &c);
    const float x0 = X[base], x1 = X[base + 1];
    X[base]     = x0 * c - x1 * sn;
    X[base + 1] = x0 * sn + x1 * c;
}

// ---------------- Flash attention: block = (b, h, 128-query tile) ----------------
// 256 threads: tid = 4*qpair + p.  Thread owns query rows (2*qpair, 2*qpair+1)
// and head-dim slice [16p, 16p+16).  K/V staged in LDS in 64-key tiles.
// __launch_bounds__(256,1): min 1 wave/EU -> VGPR cap 256+, no scratch spill.
// (no launch_bounds => default flat-wg-size 1024 => 64-VGPR cap => massive spill, R3 lesson)
// mask: allowed j < i (strict), except i==0 -> only j==0
#define TQ 128
#define TJ 64
#define MINIT -1.0e30f

__global__ __launch_bounds__(256, 1)
void flash_attn_kernel(const float* __restrict__ Qh,
                       const float* __restrict__ Kh,
                       const float* __restrict__ Vh,
                       float* __restrict__ ctx)
{
    const int nt = SEQ / TQ;                 // 16 query tiles
    const int t  = nt - 1 - blockIdx.x;      // heavy tiles dispatched first
    const int h  = blockIdx.y, b = blockIdx.z;
    const int tid = threadIdx.x;
    const int p  = tid & 3;
    const int qp = tid >> 2;                 // 0..63
    const int r0 = t * TQ;
    const int i0 = r0 + qp * 2;
    const int i1 = i0 + 1;
    const int dbase = p * 16;

    __shared__ __align__(16) float sk[TJ][HD];
    __shared__ __align__(16) float sv[TJ][HD];

    const long base = ((long)(b * NH + h)) * SEQ * HD;

    // Q fragments in registers (pre-scaled): 2 rows x 16 dims
    float q0r[16], q1r[16];
    {
        const float4* qa = (const float4*)(Qh + base + (long)i0 * HD + dbase);
        const float4* qb = (const float4*)(Qh + base + (long)i1 * HD + dbase);
        #pragma unroll
        for (int u = 0; u < 4; ++u) {
            float4 va = qa[u], vb = qb[u];
            q0r[4*u+0] = va.x * SCALE; q0r[4*u+1] = va.y * SCALE;
            q0r[4*u+2] = va.z * SCALE; q0r[4*u+3] = va.w * SCALE;
            q1r[4*u+0] = vb.x * SCALE; q1r[4*u+1] = vb.y * SCALE;
            q1r[4*u+2] = vb.z * SCALE; q1r[4*u+3] = vb.w * SCALE;
        }
    }

    float acc0[16], acc1[16];
    #pragma unroll
    for (int d = 0; d < 16; ++d) { acc0[d] = 0.f; acc1[d] = 0.f; }
    float m0 = MINIT, m1 = MINIT, l0 = 0.f, l1 = 0.f;

    const int njt = (r0 + TQ - 2) / TJ + 1;   // = 2t+2 key tiles

    for (int jt = 0; jt < njt; ++jt) {
        const int jbase = jt * TJ;

        __syncthreads();   // protect previous-iteration LDS reads
        #pragma unroll
        for (int u = 0; u < 4; ++u) {
            int idx = u * 1024 + tid * 4;
            int r = idx >> 6, c = idx & 63;
            *(float4*)&sk[r][c] = *(const float4*)(Kh + base + (long)(jbase + r) * HD + c);
            *(float4*)&sv[r][c] = *(const float4*)(Vh + base + (long)(jbase + r) * HD + c);
        }
        __syncthreads();

        const bool masked_tile = (jbase + TJ > r0);

        #pragma unroll
        for (int c8 = 0; c8 < 8; ++c8) {
            float s0[8], s1[8];
            // partial dots over this thread's 16 dims
            #pragma unroll
            for (int kk = 0; kk < 8; ++kk) {
                const int jj = c8 * 8 + kk;
                const float4* kp = (const float4*)&sk[jj][dbase];
                float d0 = 0.f, d1 = 0.f;
                #pragma unroll
                for (int u = 0; u < 4; ++u) {
                    float4 kv = kp[u];
                    d0 += kv.x * q0r[4*u+0] + kv.y * q0r[4*u+1]
                        + kv.z * q0r[4*u+2] + kv.w * q0r[4*u+3];
                    d1 += kv.x * q1r[4*u+0] + kv.y * q1r[4*u+1]
                        + kv.z * q1r[4*u+2] + kv.w * q1r[4*u+3];
                }
                s0[kk] = d0; s1[kk] = d1;
            }
            // reduce partials across the 4 p-lanes (low 2 bits of lane id)
            #pragma unroll
            for (int kk = 0; kk < 8; ++kk) {
                s0[kk] += __shfl_xor(s0[kk], 1, 64);
                s0[kk] += __shfl_xor(s0[kk], 2, 64);
                s1[kk] += __shfl_xor(s1[kk], 1, 64);
                s1[kk] += __shfl_xor(s1[kk], 2, 64);
            }
            // causal mask (masked score -> -inf; m stays finite so no NaN)
            if (masked_tile) {
                #pragma unroll
                for (int kk = 0; kk < 8; ++kk) {
                    const int j = jbase + c8 * 8 + kk;
                    const bool a0 = (j < i0) || (i0 == 0 && j == 0);
                    const bool a1 = (j < i1);
                    if (!a0) s0[kk] = -INFINITY;
                    if (!a1) s1[kk] = -INFINITY;
                }
            }
            // online softmax update (branch-free: m finite always)
            float mx0 = s0[0], mx1 = s1[0];
            #pragma unroll
            for (int kk = 1; kk < 8; ++kk) { mx0 = fmaxf(mx0, s0[kk]); mx1 = fmaxf(mx1, s1[kk]); }
            const float mn0 = fmaxf(m0, mx0), mn1 = fmaxf(m1, mx1);
            const float a0 = __expf(m0 - mn0);
            const float a1 = __expf(m1 - mn1);
            float ss0 = 0.f, ss1 = 0.f;
            #pragma unroll
            for (int kk = 0; kk < 8; ++kk) {
                const float e0 = __expf(s0[kk] - mn0);
                const float e1 = __expf(s1[kk] - mn1);
                s0[kk] = e0; s1[kk] = e1;
                ss0 += e0; ss1 += e1;
            }
            l0 = l0 * a0 + ss0;
            l1 = l1 * a1 + ss1;
            m0 = mn0; m1 = mn1;
            #pragma unroll
            for (int d = 0; d < 16; ++d) { acc0[d] *= a0; acc1[d] *= a1; }
            // PV accumulate (V read shared by both query rows)
            #pragma unroll
            for (int kk = 0; kk < 8; ++kk) {
                const int jj = c8 * 8 + kk;
                const float4* vp = (const float4*)&sv[jj][dbase];
                const float e0 = s0[kk], e1 = s1[kk];
                #pragma unroll
                for (int u = 0; u < 4; ++u) {
                    float4 vv = vp[u];
                    acc0[4*u+0] += e0 * vv.x; acc0[4*u+1] += e0 * vv.y;
                    acc0[4*u+2] += e0 * vv.z; acc0[4*u+3] += e0 * vv.w;
                    acc1[4*u+0] += e1 * vv.x; acc1[4*u+1] += e1 * vv.y;
                    acc1[4*u+2] += e1 * vv.z; acc1[4*u+3] += e1 * vv.w;
                }
            }
        }
    }

    // epilogue: ctx layout [B, S, DATTN]
    const float inv0 = 1.f / l0, inv1 = 1.f / l1;
    float* o0 = ctx + ((long)(b * SEQ + i0)) * DATTN + h * HD + dbase;
    float* o1 = ctx + ((long)(b * SEQ + i1)) * DATTN + h * HD + dbase;
    #pragma unroll
    for (int u = 0; u < 4; ++u) {
        float4 w0, w1;
        w0.x = acc0[4*u+0] * inv0; w0.y = acc0[4*u+1] * inv0;
        w0.z = acc0[4*u+2] * inv0; w0.w = acc0[4*u+3] * inv0;
        w1.x = acc1[4*u+0] * inv1; w1.y = acc1[4*u+1] * inv1;
        w1.z = acc1[4*u+2] * inv1; w1.w = acc1[4*u+3] * inv1;
        *(float4*)(o0 + 4*u) = w0;
        *(float4*)(o1 + 4*u) = w1;
    }
}

extern "C" void kernel_launch(void* const* d_in, const int* in_sizes, int n_in,
                              void* d_out, int out_size, void* d_ws, size_t ws_size,
                              hipStream_t stream) {
    const float* q  = (const float*)d_in[0];
    const float* k  = (const float*)d_in[1];
    const float* v  = (const float*)d_in[2];
    const float* Wq = (const float*)d_in[3];
    const float* Wk = (const float*)d_in[4];
    const float* Wv = (const float*)d_in[5];
    const float* Wo = (const float*)d_in[6];
    float* out = (float*)d_out;

    // workspace layout (fp32): Qh | Kh | Vh | ctx  — 4 x 16 MB = 64 MB
    const long TSZ = (long)BATCH * NH * SEQ * HD;   // 4,194,304
    float* Qh  = (float*)d_ws;
    float* Kh  = Qh + TSZ;
    float* Vh  = Kh + TSZ;
    float* ctx = Vh + TSZ;

    dim3 gemm_grid(MM / BM, DATTN / BN);   // (64, 16)
    gemm_proj_kernel<<<gemm_grid, 256, 0, stream>>>(q, Wq, Qh);
    gemm_proj_kernel<<<gemm_grid, 256, 0, stream>>>(k, Wk, Kh);
    gemm_proj_kernel<<<gemm_grid, 256, 0, stream>>>(v, Wv, Vh);

    const int npairs = BATCH * NH * SEQ * (HD / 2);  // 2,097,152
    rope_kernel<<<(npairs + 255) / 256, 256, 0, stream>>>(Qh);
    rope_kernel<<<(npairs + 255) / 256, 256, 0, stream>>>(Kh);

    flash_attn_kernel<<<dim3(SEQ / TQ, NH, BATCH), 256, 0, stream>>>(Qh, Kh, Vh, ctx);

    gemm_out_kernel<<<gemm_grid, 256, 0, stream>>>(ctx, Wo, out);
}

// Round 6
// 1776.075 us; speedup vs baseline: 4.2268x; 3.3056x over previous
//
#include <hip/hip_runtime.h>
#include <hip/hip_bf16.h>

// Problem constants (fixed shapes)
#define BATCH 2
#define SEQ   2048
#define EMB   1024
#define DATTN 1024
#define NH    16
#define HD    64
#define MM    (BATCH*SEQ)        // 4096 rows
#define SCALE 0.03125f           // 1/sqrt(1024)

// ---------------- GEMM: C = A @ W^T, A fp32 [M,K], W fp32 [N,K] ----------------
// Stores fp32 into head layout [B, H, S, HD]:  (((b*NH+h)*SEQ)+s)*HD + d
#define BM 64
#define BN 64
#define BK 16

__global__ void gemm_proj_kernel(const float* __restrict__ A,
                                 const float* __restrict__ W,
                                 float* __restrict__ Chead)
{
    const int K = EMB;
    __shared__ float As[BM][BK + 1];
    __shared__ float Bs[BN][BK + 1];
    const int tid = threadIdx.x;
    const int tx = tid & 15, ty = tid >> 4;
    const int m0 = blockIdx.x * BM;
    const int n0 = blockIdx.y * BN;

    float acc[4][4] = {};

    for (int kt = 0; kt < K; kt += BK) {
        int idx = tid * 4;
        int row = idx >> 4;      // /16
        int col = idx & 15;      // 0,4,8,12
        float4 av = *(const float4*)(A + (long)(m0 + row) * K + kt + col);
        float4 wv = *(const float4*)(W + (long)(n0 + row) * K + kt + col);
        As[row][col + 0] = av.x; As[row][col + 1] = av.y;
        As[row][col + 2] = av.z; As[row][col + 3] = av.w;
        Bs[row][col + 0] = wv.x; Bs[row][col + 1] = wv.y;
        Bs[row][col + 2] = wv.z; Bs[row][col + 3] = wv.w;
        __syncthreads();

        #pragma unroll
        for (int kk = 0; kk < BK; ++kk) {
            float a[4], b[4];
            #pragma unroll
            for (int r = 0; r < 4; ++r) a[r] = As[ty * 4 + r][kk];
            #pragma unroll
            for (int c = 0; c < 4; ++c) b[c] = Bs[tx * 4 + c][kk];
            #pragma unroll
            for (int r = 0; r < 4; ++r)
                #pragma unroll
                for (int c = 0; c < 4; ++c)
                    acc[r][c] += a[r] * b[c];
        }
        __syncthreads();
    }

    #pragma unroll
    for (int r = 0; r < 4; ++r) {
        const int m = m0 + ty * 4 + r;
        const int b = m >> 11;          // /SEQ
        const int s = m & (SEQ - 1);
        #pragma unroll
        for (int c = 0; c < 4; ++c) {
            const int n = n0 + tx * 4 + c;
            const int h = n >> 6;       // /HD
            const int d = n & (HD - 1);
            Chead[((((long)(b * NH + h)) * SEQ + s) << 6) + d] = acc[r][c];
        }
    }
}

// ---------------- GEMM: out = ctx @ Wo^T, ctx fp32 [M,K], Wo fp32 [N,K], out fp32 ----------------
__global__ void gemm_out_kernel(const float* __restrict__ A,
                                const float* __restrict__ W,
                                float* __restrict__ C)
{
    const int K = DATTN, N = EMB;
    __shared__ float As[BM][BK + 1];
    __shared__ float Bs[BN][BK + 1];
    const int tid = threadIdx.x;
    const int tx = tid & 15, ty = tid >> 4;
    const int m0 = blockIdx.x * BM;
    const int n0 = blockIdx.y * BN;

    float acc[4][4] = {};

    for (int kt = 0; kt < K; kt += BK) {
        int idx = tid * 4;
        int row = idx >> 4;
        int col = idx & 15;
        float4 av = *(const float4*)(A + (long)(m0 + row) * K + kt + col);
        float4 wv = *(const float4*)(W + (long)(n0 + row) * K + kt + col);
        As[row][col + 0] = av.x; As[row][col + 1] = av.y;
        As[row][col + 2] = av.z; As[row][col + 3] = av.w;
        Bs[row][col + 0] = wv.x; Bs[row][col + 1] = wv.y;
        Bs[row][col + 2] = wv.z; Bs[row][col + 3] = wv.w;
        __syncthreads();

        #pragma unroll
        for (int kk = 0; kk < BK; ++kk) {
            float a[4], b[4];
            #pragma unroll
            for (int r = 0; r < 4; ++r) a[r] = As[ty * 4 + r][kk];
            #pragma unroll
            for (int c = 0; c < 4; ++c) b[c] = Bs[tx * 4 + c][kk];
            #pragma unroll
            for (int r = 0; r < 4; ++r)
                #pragma unroll
                for (int c = 0; c < 4; ++c)
                    acc[r][c] += a[r] * b[c];
        }
        __syncthreads();
    }

    #pragma unroll
    for (int r = 0; r < 4; ++r) {
        const int m = m0 + ty * 4 + r;
        #pragma unroll
        for (int c = 0; c < 4; ++c) {
            const int n = n0 + tx * 4 + c;
            C[(long)m * N + n] = acc[r][c];
        }
    }
}

// ---------------- RoPE (in-place on head-layout tensor [B,H,S,HD]) ----------------
__global__ void rope_kernel(float* __restrict__ X)
{
    const int t = blockIdx.x * blockDim.x + threadIdx.x;
    if (t >= BATCH * NH * SEQ * (HD / 2)) return;
    const int p  = t & 31;               // pair index in head dim
    const int s  = (t >> 5) & (SEQ - 1);
    const int bh = t >> 16;              // b*NH + h
    const long base = (((long)bh * SEQ + s) << 6) + p * 2;
    const float inv_freq = powf(10000.0f, -(float)(2 * p) / 64.0f);
    const float ang = (float)s * inv_freq;
    float c, sn;
    __sincosf(ang, &sn, &c);
    const float x0 = X[base], x1 = X[base + 1];
    X[base]     = x0 * c - x1 * sn;
    X[base + 1] = x0 * sn + x1 * c;
}

// ---------------- Flash attention: block = (b, h, 128-query tile) ----------------
// 256 threads: tid = 4*qpair + p.  Thread owns query rows (2*qpair, 2*qpair+1)
// and head-dim slice [16p, 16p+16).  K/V staged in LDS in 64-key tiles.
// CHUNK LOOP IS NOT UNROLLED (unroll 1): full unroll interleaved 8 chunks'
// live ranges -> >256 VGPR -> scratch spill (R4/R5 lesson: 6-14 GB spill traffic).
// mask: allowed j < i (strict), except i==0 -> only j==0
#define TQ 128
#define TJ 64
#define MINIT -1.0e30f

__global__ __launch_bounds__(256, 1)
void flash_attn_kernel(const float* __restrict__ Qh,
                       const float* __restrict__ Kh,
                       const float* __restrict__ Vh,
                       float* __restrict__ ctx)
{
    const int nt = SEQ / TQ;                 // 16 query tiles
    const int t  = nt - 1 - blockIdx.x;      // heavy tiles dispatched first
    const int h  = blockIdx.y, b = blockIdx.z;
    const int tid = threadIdx.x;
    const int p  = tid & 3;
    const int qp = tid >> 2;                 // 0..63
    const int r0 = t * TQ;
    const int i0 = r0 + qp * 2;
    const int i1 = i0 + 1;
    const int dbase = p * 16;

    __shared__ __align__(16) float sk[TJ][HD];
    __shared__ __align__(16) float sv[TJ][HD];

    const long base = ((long)(b * NH + h)) * SEQ * HD;

    // Q fragments in registers (pre-scaled): 2 rows x 16 dims
    float q0r[16], q1r[16];
    {
        const float4* qa = (const float4*)(Qh + base + (long)i0 * HD + dbase);
        const float4* qb = (const float4*)(Qh + base + (long)i1 * HD + dbase);
        #pragma unroll
        for (int u = 0; u < 4; ++u) {
            float4 va = qa[u], vb = qb[u];
            q0r[4*u+0] = va.x * SCALE; q0r[4*u+1] = va.y * SCALE;
            q0r[4*u+2] = va.z * SCALE; q0r[4*u+3] = va.w * SCALE;
            q1r[4*u+0] = vb.x * SCALE; q1r[4*u+1] = vb.y * SCALE;
            q1r[4*u+2] = vb.z * SCALE; q1r[4*u+3] = vb.w * SCALE;
        }
    }

    float acc0[16], acc1[16];
    #pragma unroll
    for (int d = 0; d < 16; ++d) { acc0[d] = 0.f; acc1[d] = 0.f; }
    float m0 = MINIT, m1 = MINIT, l0 = 0.f, l1 = 0.f;

    const int njt = (r0 + TQ - 2) / TJ + 1;   // = 2t+2 key tiles

    for (int jt = 0; jt < njt; ++jt) {
        const int jbase = jt * TJ;

        __syncthreads();   // protect previous-iteration LDS reads
        #pragma unroll
        for (int u = 0; u < 4; ++u) {
            int idx = u * 1024 + tid * 4;
            int r = idx >> 6, c = idx & 63;
            *(float4*)&sk[r][c] = *(const float4*)(Kh + base + (long)(jbase + r) * HD + c);
            *(float4*)&sv[r][c] = *(const float4*)(Vh + base + (long)(jbase + r) * HD + c);
        }
        __syncthreads();

        const bool masked_tile = (jbase + TJ > r0);

        #pragma unroll 1
        for (int c8 = 0; c8 < 8; ++c8) {
            float s0[8], s1[8];
            // partial dots over this thread's 16 dims
            #pragma unroll
            for (int kk = 0; kk < 8; ++kk) {
                const int jj = c8 * 8 + kk;
                const float4* kp = (const float4*)&sk[jj][dbase];
                float d0 = 0.f, d1 = 0.f;
                #pragma unroll
                for (int u = 0; u < 4; ++u) {
                    float4 kv = kp[u];
                    d0 += kv.x * q0r[4*u+0] + kv.y * q0r[4*u+1]
                        + kv.z * q0r[4*u+2] + kv.w * q0r[4*u+3];
                    d1 += kv.x * q1r[4*u+0] + kv.y * q1r[4*u+1]
                        + kv.z * q1r[4*u+2] + kv.w * q1r[4*u+3];
                }
                s0[kk] = d0; s1[kk] = d1;
            }
            // reduce partials across the 4 p-lanes (low 2 bits of lane id)
            #pragma unroll
            for (int kk = 0; kk < 8; ++kk) {
                s0[kk] += __shfl_xor(s0[kk], 1, 64);
                s0[kk] += __shfl_xor(s0[kk], 2, 64);
                s1[kk] += __shfl_xor(s1[kk], 1, 64);
                s1[kk] += __shfl_xor(s1[kk], 2, 64);
            }
            // causal mask (masked score -> -inf; m stays finite so no NaN)
            if (masked_tile) {
                #pragma unroll
                for (int kk = 0; kk < 8; ++kk) {
                    const int j = jbase + c8 * 8 + kk;
                    const bool a0 = (j < i0) || (i0 == 0 && j == 0);
                    const bool a1 = (j < i1);
                    if (!a0) s0[kk] = -INFINITY;
                    if (!a1) s1[kk] = -INFINITY;
                }
            }
            // online softmax update (branch-free: m finite always)
            float mx0 = s0[0], mx1 = s1[0];
            #pragma unroll
            for (int kk = 1; kk < 8; ++kk) { mx0 = fmaxf(mx0, s0[kk]); mx1 = fmaxf(mx1, s1[kk]); }
            const float mn0 = fmaxf(m0, mx0), mn1 = fmaxf(m1, mx1);
            const float a0 = __expf(m0 - mn0);
            const float a1 = __expf(m1 - mn1);
            float ss0 = 0.f, ss1 = 0.f;
            #pragma unroll
            for (int kk = 0; kk < 8; ++kk) {
                const float e0 = __expf(s0[kk] - mn0);
                const float e1 = __expf(s1[kk] - mn1);
                s0[kk] = e0; s1[kk] = e1;
                ss0 += e0; ss1 += e1;
            }
            l0 = l0 * a0 + ss0;
            l1 = l1 * a1 + ss1;
            m0 = mn0; m1 = mn1;
            #pragma unroll
            for (int d = 0; d < 16; ++d) { acc0[d] *= a0; acc1[d] *= a1; }
            // PV accumulate (V read shared by both query rows)
            #pragma unroll
            for (int kk = 0; kk < 8; ++kk) {
                const int jj = c8 * 8 + kk;
                const float4* vp = (const float4*)&sv[jj][dbase];
                const float e0 = s0[kk], e1 = s1[kk];
                #pragma unroll
                for (int u = 0; u < 4; ++u) {
                    float4 vv = vp[u];
                    acc0[4*u+0] += e0 * vv.x; acc0[4*u+1] += e0 * vv.y;
                    acc0[4*u+2] += e0 * vv.z; acc0[4*u+3] += e0 * vv.w;
                    acc1[4*u+0] += e1 * vv.x; acc1[4*u+1] += e1 * vv.y;
                    acc1[4*u+2] += e1 * vv.z; acc1[4*u+3] += e1 * vv.w;
                }
            }
        }
    }

    // epilogue: ctx layout [B, S, DATTN]
    const float inv0 = 1.f / l0, inv1 = 1.f / l1;
    float* o0 = ctx + ((long)(b * SEQ + i0)) * DATTN + h * HD + dbase;
    float* o1 = ctx + ((long)(b * SEQ + i1)) * DATTN + h * HD + dbase;
    #pragma unroll
    for (int u = 0; u < 4; ++u) {
        float4 w0, w1;
        w0.x = acc0[4*u+0] * inv0; w0.y = acc0[4*u+1] * inv0;
        w0.z = acc0[4*u+2] * inv0; w0.w = acc0[4*u+3] * inv0;
        w1.x = acc1[4*u+0] * inv1; w1.y = acc1[4*u+1] * inv1;
        w1.z = acc1[4*u+2] * inv1; w1.w = acc1[4*u+3] * inv1;
        *(float4*)(o0 + 4*u) = w0;
        *(float4*)(o1 + 4*u) = w1;
    }
}

extern "C" void kernel_launch(void* const* d_in, const int* in_sizes, int n_in,
                              void* d_out, int out_size, void* d_ws, size_t ws_size,
                              hipStream_t stream) {
    const float* q  = (const float*)d_in[0];
    const float* k  = (const float*)d_in[1];
    const float* v  = (const float*)d_in[2];
    const float* Wq = (const float*)d_in[3];
    const float* Wk = (const float*)d_in[4];
    const float* Wv = (const float*)d_in[5];
    const float* Wo = (const float*)d_in[6];
    float* out = (float*)d_out;

    // workspace layout (fp32): Qh | Kh | Vh | ctx  — 4 x 16 MB = 64 MB
    const long TSZ = (long)BATCH * NH * SEQ * HD;   // 4,194,304
    float* Qh  = (float*)d_ws;
    float* Kh  = Qh + TSZ;
    float* Vh  = Kh + TSZ;
    float* ctx = Vh + TSZ;

    dim3 gemm_grid(MM / BM, DATTN / BN);   // (64, 16)
    gemm_proj_kernel<<<gemm_grid, 256, 0, stream>>>(q, Wq, Qh);
    gemm_proj_kernel<<<gemm_grid, 256, 0, stream>>>(k, Wk, Kh);
    gemm_proj_kernel<<<gemm_grid, 256, 0, stream>>>(v, Wv, Vh);

    const int npairs = BATCH * NH * SEQ * (HD / 2);  // 2,097,152
    rope_kernel<<<(npairs + 255) / 256, 256, 0, stream>>>(Qh);
    rope_kernel<<<(npairs + 255) / 256, 256, 0, stream>>>(Kh);

    flash_attn_kernel<<<dim3(SEQ / TQ, NH, BATCH), 256, 0, stream>>>(Qh, Kh, Vh, ctx);

    gemm_out_kernel<<<gemm_grid, 256, 0, stream>>>(ctx, Wo, out);
}

// Round 7
// 1072.116 us; speedup vs baseline: 7.0021x; 1.6566x over previous
//
#include <hip/hip_runtime.h>
#include <hip/hip_bf16.h>

// Problem constants (fixed shapes)
#define BATCH 2
#define SEQ   2048
#define EMB   1024
#define DATTN 1024
#define NH    16
#define HD    64
#define MM    (BATCH*SEQ)        // 4096 rows
#define SCALE 0.03125f           // 1/sqrt(1024)

using bf16x8 = __attribute__((ext_vector_type(8))) short;   // 8 bf16 (4 VGPRs)
using f32x4  = __attribute__((ext_vector_type(4))) float;   // MFMA C/D

__device__ inline short f2bf(float x) {
    __hip_bfloat16 b = __float2bfloat16(x);
    return *reinterpret_cast<short*>(&b);
}

// ---------------- MFMA GEMM tiles: 128x128 block, 4 waves (2x2 of 64x64) ----------------
// LDS rows padded: 32 bf16 data + 8 pad = 40 shorts (80 B) -> 16B-aligned frags, 2-way-max bank alias
#define LDA 40

// Fused Q/K/V projection: C = A @ W^T (A fp32 [4096,1024], W fp32 [1024,1024]),
// output fp32 in head layout [B,H,S,HD]. blockIdx.z selects (A,W,C) triple.
__global__ __launch_bounds__(256)
void gemm_proj_mfma(const float* __restrict__ q, const float* __restrict__ k,
                    const float* __restrict__ v,
                    const float* __restrict__ Wq, const float* __restrict__ Wk,
                    const float* __restrict__ Wv,
                    float* __restrict__ Qh, float* __restrict__ Kh, float* __restrict__ Vh)
{
    const float* A; const float* W; float* C;
    if (blockIdx.z == 0)      { A = q; W = Wq; C = Qh; }
    else if (blockIdx.z == 1) { A = k; W = Wk; C = Kh; }
    else                      { A = v; W = Wv; C = Vh; }

    __shared__ short sA[128 * LDA];
    __shared__ short sB[128 * LDA];

    const int tid  = threadIdx.x;
    const int wave = tid >> 6, lane = tid & 63;
    const int quad = lane >> 4, l16 = lane & 15;
    const int wm = (wave >> 1) * 64, wn = (wave & 1) * 64;
    const long m0 = (long)blockIdx.x * 128, n0 = (long)blockIdx.y * 128;

    f32x4 acc[4][4];
    #pragma unroll
    for (int i = 0; i < 4; ++i)
        #pragma unroll
        for (int j = 0; j < 4; ++j) acc[i][j] = (f32x4){0.f, 0.f, 0.f, 0.f};

    for (int kt = 0; kt < EMB; kt += 32) {
        __syncthreads();
        #pragma unroll
        for (int u = 0; u < 4; ++u) {
            int i  = u * 256 + tid;      // 0..1023
            int r  = i >> 3;             // 0..127
            int c4 = (i & 7) * 4;        // 0..28
            float4 av = *(const float4*)(A + (m0 + r) * EMB + kt + c4);
            float4 wv = *(const float4*)(W + (n0 + r) * EMB + kt + c4);
            short4 as, bs;
            as.x = f2bf(av.x); as.y = f2bf(av.y); as.z = f2bf(av.z); as.w = f2bf(av.w);
            bs.x = f2bf(wv.x); bs.y = f2bf(wv.y); bs.z = f2bf(wv.z); bs.w = f2bf(wv.w);
            *(short4*)&sA[r * LDA + c4] = as;
            *(short4*)&sB[r * LDA + c4] = bs;
        }
        __syncthreads();

        // A-frag: m = l16, k = quad*8 + j   (m120-verified operand layout)
        bf16x8 af[4], bfr[4];
        #pragma unroll
        for (int rt = 0; rt < 4; ++rt)
            af[rt] = *(const bf16x8*)&sA[(wm + rt * 16 + l16) * LDA + quad * 8];
        #pragma unroll
        for (int ct = 0; ct < 4; ++ct)
            bfr[ct] = *(const bf16x8*)&sB[(wn + ct * 16 + l16) * LDA + quad * 8];
        #pragma unroll
        for (int rt = 0; rt < 4; ++rt)
            #pragma unroll
            for (int ct = 0; ct < 4; ++ct)
                acc[rt][ct] = __builtin_amdgcn_mfma_f32_16x16x32_bf16(
                    af[rt], bfr[ct], acc[rt][ct], 0, 0, 0);
    }

    // C/D layout: col = l16, row = quad*4 + reg (m89-verified). Scatter to head layout.
    #pragma unroll
    for (int rt = 0; rt < 4; ++rt) {
        #pragma unroll
        for (int ct = 0; ct < 4; ++ct) {
            #pragma unroll
            for (int reg = 0; reg < 4; ++reg) {
                const long row = m0 + wm + rt * 16 + quad * 4 + reg;
                const long col = n0 + wn + ct * 16 + l16;
                const int bb = (int)(row >> 11), ss = (int)(row & (SEQ - 1));
                const int hh = (int)(col >> 6),  dd = (int)(col & (HD - 1));
                Qh[0]; // no-op; keeps compiler happy about unused warnings
                C[(((long)(bb * NH + hh)) << 17) + ((long)ss << 6) + dd] = acc[rt][ct][reg];
            }
        }
    }
}

// Output GEMM: out = ctx @ Wo^T, plain [4096,1024] fp32 output
__global__ __launch_bounds__(256)
void gemm_out_mfma(const float* __restrict__ A, const float* __restrict__ W,
                   float* __restrict__ C)
{
    __shared__ short sA[128 * LDA];
    __shared__ short sB[128 * LDA];

    const int tid  = threadIdx.x;
    const int wave = tid >> 6, lane = tid & 63;
    const int quad = lane >> 4, l16 = lane & 15;
    const int wm = (wave >> 1) * 64, wn = (wave & 1) * 64;
    const long m0 = (long)blockIdx.x * 128, n0 = (long)blockIdx.y * 128;

    f32x4 acc[4][4];
    #pragma unroll
    for (int i = 0; i < 4; ++i)
        #pragma unroll
        for (int j = 0; j < 4; ++j) acc[i][j] = (f32x4){0.f, 0.f, 0.f, 0.f};

    for (int kt = 0; kt < DATTN; kt += 32) {
        __syncthreads();
        #pragma unroll
        for (int u = 0; u < 4; ++u) {
            int i  = u * 256 + tid;
            int r  = i >> 3;
            int c4 = (i & 7) * 4;
            float4 av = *(const float4*)(A + (m0 + r) * DATTN + kt + c4);
            float4 wv = *(const float4*)(W + (n0 + r) * DATTN + kt + c4);
            short4 as, bs;
            as.x = f2bf(av.x); as.y = f2bf(av.y); as.z = f2bf(av.z); as.w = f2bf(av.w);
            bs.x = f2bf(wv.x); bs.y = f2bf(wv.y); bs.z = f2bf(wv.z); bs.w = f2bf(wv.w);
            *(short4*)&sA[r * LDA + c4] = as;
            *(short4*)&sB[r * LDA + c4] = bs;
        }
        __syncthreads();

        bf16x8 af[4], bfr[4];
        #pragma unroll
        for (int rt = 0; rt < 4; ++rt)
            af[rt] = *(const bf16x8*)&sA[(wm + rt * 16 + l16) * LDA + quad * 8];
        #pragma unroll
        for (int ct = 0; ct < 4; ++ct)
            bfr[ct] = *(const bf16x8*)&sB[(wn + ct * 16 + l16) * LDA + quad * 8];
        #pragma unroll
        for (int rt = 0; rt < 4; ++rt)
            #pragma unroll
            for (int ct = 0; ct < 4; ++ct)
                acc[rt][ct] = __builtin_amdgcn_mfma_f32_16x16x32_bf16(
                    af[rt], bfr[ct], acc[rt][ct], 0, 0, 0);
    }

    #pragma unroll
    for (int rt = 0; rt < 4; ++rt) {
        #pragma unroll
        for (int ct = 0; ct < 4; ++ct) {
            #pragma unroll
            for (int reg = 0; reg < 4; ++reg) {
                const long row = m0 + wm + rt * 16 + quad * 4 + reg;
                const long col = n0 + wn + ct * 16 + l16;
                C[row * EMB + col] = acc[rt][ct][reg];
            }
        }
    }
}

// ---------------- RoPE (in-place on head-layout tensor [B,H,S,HD]) ----------------
__global__ void rope_kernel(float* __restrict__ X)
{
    const int t = blockIdx.x * blockDim.x + threadIdx.x;
    if (t >= BATCH * NH * SEQ * (HD / 2)) return;
    const int p  = t & 31;               // pair index in head dim
    const int s  = (t >> 5) & (SEQ - 1);
    const int bh = t >> 16;              // b*NH + h
    const long base = (((long)bh * SEQ + s) << 6) + p * 2;
    const float inv_freq = powf(10000.0f, -(float)(2 * p) / 64.0f);
    const float ang = (float)s * inv_freq;
    float c, sn;
    __sincosf(ang, &sn, &c);
    const float x0 = X[base], x1 = X[base + 1];
    X[base]     = x0 * c - x1 * sn;
    X[base + 1] = x0 * sn + x1 * c;
}

// ---------------- Flash attention: block = (b, h, 64-query tile) ----------------
// 256 threads: tid = 4*q + p. Thread owns ONE query row (qp = tid>>2) and
// head-dim slice [16p,16p+16). K/V staged in LDS in 64-key tiles.
// CHUNK LOOP NOT UNROLLED (unroll 1): full unroll -> >256 VGPR -> spill (R4/R5 lesson).
// mask: allowed j < i (strict), except i==0 -> only j==0
#define TQ 64
#define TJ 64
#define MINIT -1.0e30f

__global__ __launch_bounds__(256, 1)
void flash_attn_kernel(const float* __restrict__ Qh,
                       const float* __restrict__ Kh,
                       const float* __restrict__ Vh,
                       float* __restrict__ ctx)
{
    const int nt = SEQ / TQ;                 // 32 query tiles
    const int t  = nt - 1 - blockIdx.x;      // heavy tiles dispatched first
    const int h  = blockIdx.y, b = blockIdx.z;
    const int tid = threadIdx.x;
    const int p  = tid & 3;
    const int qp = tid >> 2;                 // 0..63
    const int r0 = t * TQ;
    const int i0 = r0 + qp;
    const int dbase = p * 16;

    __shared__ __align__(16) float sk[TJ][HD];
    __shared__ __align__(16) float sv[TJ][HD];

    const long base = ((long)(b * NH + h)) * SEQ * HD;

    // Q fragment in registers (pre-scaled): 1 row x 16 dims
    float q0r[16];
    {
        const float4* qa = (const float4*)(Qh + base + (long)i0 * HD + dbase);
        #pragma unroll
        for (int u = 0; u < 4; ++u) {
            float4 va = qa[u];
            q0r[4*u+0] = va.x * SCALE; q0r[4*u+1] = va.y * SCALE;
            q0r[4*u+2] = va.z * SCALE; q0r[4*u+3] = va.w * SCALE;
        }
    }

    float acc0[16];
    #pragma unroll
    for (int d = 0; d < 16; ++d) acc0[d] = 0.f;
    float m0 = MINIT, l0 = 0.f;

    const int njt = (r0 + TQ - 2) / TJ + 1;   // key tiles (covers j <= r0+TQ-2)

    for (int jt = 0; jt < njt; ++jt) {
        const int jbase = jt * TJ;

        __syncthreads();   // protect previous-iteration LDS reads
        #pragma unroll
        for (int u = 0; u < 4; ++u) {
            int idx = u * 1024 + tid * 4;
            int r = idx >> 6, c = idx & 63;
            *(float4*)&sk[r][c] = *(const float4*)(Kh + base + (long)(jbase + r) * HD + c);
            *(float4*)&sv[r][c] = *(const float4*)(Vh + base + (long)(jbase + r) * HD + c);
        }
        __syncthreads();

        const bool masked_tile = (jbase + TJ > r0);

        #pragma unroll 1
        for (int c8 = 0; c8 < 8; ++c8) {
            float s0[8];
            #pragma unroll
            for (int kk = 0; kk < 8; ++kk) {
                const int jj = c8 * 8 + kk;
                const float4* kp = (const float4*)&sk[jj][dbase];
                float d0 = 0.f;
                #pragma unroll
                for (int u = 0; u < 4; ++u) {
                    float4 kv = kp[u];
                    d0 += kv.x * q0r[4*u+0] + kv.y * q0r[4*u+1]
                        + kv.z * q0r[4*u+2] + kv.w * q0r[4*u+3];
                }
                s0[kk] = d0;
            }
            // reduce partials across the 4 p-lanes (low 2 bits of lane id)
            #pragma unroll
            for (int kk = 0; kk < 8; ++kk) {
                s0[kk] += __shfl_xor(s0[kk], 1, 64);
                s0[kk] += __shfl_xor(s0[kk], 2, 64);
            }
            // causal mask (masked score -> -inf; m stays finite so no NaN)
            if (masked_tile) {
                #pragma unroll
                for (int kk = 0; kk < 8; ++kk) {
                    const int j = jbase + c8 * 8 + kk;
                    const bool ok = (j < i0) || (i0 == 0 && j == 0);
                    if (!ok) s0[kk] = -INFINITY;
                }
            }
            // online softmax update
            float mx0 = s0[0];
            #pragma unroll
            for (int kk = 1; kk < 8; ++kk) mx0 = fmaxf(mx0, s0[kk]);
            const float mn0 = fmaxf(m0, mx0);
            const float a0 = __expf(m0 - mn0);
            float ss0 = 0.f;
            #pragma unroll
            for (int kk = 0; kk < 8; ++kk) {
                const float e0 = __expf(s0[kk] - mn0);
                s0[kk] = e0;
                ss0 += e0;
            }
            l0 = l0 * a0 + ss0;
            m0 = mn0;
            #pragma unroll
            for (int d = 0; d < 16; ++d) acc0[d] *= a0;
            // PV accumulate
            #pragma unroll
            for (int kk = 0; kk < 8; ++kk) {
                const int jj = c8 * 8 + kk;
                const float4* vp = (const float4*)&sv[jj][dbase];
                const float e0 = s0[kk];
                #pragma unroll
                for (int u = 0; u < 4; ++u) {
                    float4 vv = vp[u];
                    acc0[4*u+0] += e0 * vv.x; acc0[4*u+1] += e0 * vv.y;
                    acc0[4*u+2] += e0 * vv.z; acc0[4*u+3] += e0 * vv.w;
                }
            }
        }
    }

    // epilogue: ctx layout [B, S, DATTN]
    const float inv0 = 1.f / l0;
    float* o0 = ctx + ((long)(b * SEQ + i0)) * DATTN + h * HD + dbase;
    #pragma unroll
    for (int u = 0; u < 4; ++u) {
        float4 w0;
        w0.x = acc0[4*u+0] * inv0; w0.y = acc0[4*u+1] * inv0;
        w0.z = acc0[4*u+2] * inv0; w0.w = acc0[4*u+3] * inv0;
        *(float4*)(o0 + 4*u) = w0;
    }
}

extern "C" void kernel_launch(void* const* d_in, const int* in_sizes, int n_in,
                              void* d_out, int out_size, void* d_ws, size_t ws_size,
                              hipStream_t stream) {
    const float* q  = (const float*)d_in[0];
    const float* k  = (const float*)d_in[1];
    const float* v  = (const float*)d_in[2];
    const float* Wq = (const float*)d_in[3];
    const float* Wk = (const float*)d_in[4];
    const float* Wv = (const float*)d_in[5];
    const float* Wo = (const float*)d_in[6];
    float* out = (float*)d_out;

    // workspace layout (fp32): Qh | Kh | Vh | ctx  — 4 x 16 MB = 64 MB
    const long TSZ = (long)BATCH * NH * SEQ * HD;   // 4,194,304
    float* Qh  = (float*)d_ws;
    float* Kh  = Qh + TSZ;
    float* Vh  = Kh + TSZ;
    float* ctx = Vh + TSZ;

    // fused Q/K/V projections: grid.z = 3, 768 blocks total (3/CU)
    gemm_proj_mfma<<<dim3(MM / 128, DATTN / 128, 3), 256, 0, stream>>>(
        q, k, v, Wq, Wk, Wv, Qh, Kh, Vh);

    const int npairs = BATCH * NH * SEQ * (HD / 2);  // 2,097,152
    rope_kernel<<<(npairs + 255) / 256, 256, 0, stream>>>(Qh);
    rope_kernel<<<(npairs + 255) / 256, 256, 0, stream>>>(Kh);

    flash_attn_kernel<<<dim3(SEQ / TQ, NH, BATCH), 256, 0, stream>>>(Qh, Kh, Vh, ctx);

    gemm_out_mfma<<<dim3(MM / 128, EMB / 128), 256, 0, stream>>>(ctx, Wo, out);
}

// Round 8
// 387.616 us; speedup vs baseline: 19.3673x; 2.7659x over previous
//
#include <hip/hip_runtime.h>
#include <hip/hip_bf16.h>

// Problem constants (fixed shapes)
#define BATCH 2
#define SEQ   2048
#define EMB   1024
#define DATTN 1024
#define NH    16
#define HD    64
#define MM    (BATCH*SEQ)        // 4096 rows
#define SCALE 0.03125f           // 1/sqrt(1024)
#define MINIT -1.0e30f

using bf16x8 = __attribute__((ext_vector_type(8))) short;   // 8 bf16 (4 VGPRs)
using f32x4  = __attribute__((ext_vector_type(4))) float;   // MFMA C/D

__device__ inline short f2bf(float x) {
    __hip_bfloat16 b = __float2bfloat16(x);
    return *reinterpret_cast<short*>(&b);
}

// load an 8-short MFMA fragment as two b64 reads (pitch 68 keeps rows only
// 8B-aligned; b128 would need 16B and pitch 72 causes 8-way bank conflicts)
__device__ inline bf16x8 ld_frag(const short* p) {
    short4 lo = *(const short4*)(p);
    short4 hi = *(const short4*)(p + 4);
    bf16x8 r;
    r[0] = lo.x; r[1] = lo.y; r[2] = lo.z; r[3] = lo.w;
    r[4] = hi.x; r[5] = hi.y; r[6] = hi.z; r[7] = hi.w;
    return r;
}

// ---------------- MFMA GEMM tiles: 128x128 block, 4 waves (2x2 of 64x64) ----------------
#define LDA 40

__global__ __launch_bounds__(256)
void gemm_proj_mfma(const float* __restrict__ q, const float* __restrict__ k,
                    const float* __restrict__ v,
                    const float* __restrict__ Wq, const float* __restrict__ Wk,
                    const float* __restrict__ Wv,
                    float* __restrict__ Qh, float* __restrict__ Kh, float* __restrict__ Vh)
{
    const float* A; const float* W; float* C;
    if (blockIdx.z == 0)      { A = q; W = Wq; C = Qh; }
    else if (blockIdx.z == 1) { A = k; W = Wk; C = Kh; }
    else                      { A = v; W = Wv; C = Vh; }

    __shared__ short sA[128 * LDA];
    __shared__ short sB[128 * LDA];

    const int tid  = threadIdx.x;
    const int wave = tid >> 6, lane = tid & 63;
    const int quad = lane >> 4, l16 = lane & 15;
    const int wm = (wave >> 1) * 64, wn = (wave & 1) * 64;
    const long m0 = (long)blockIdx.x * 128, n0 = (long)blockIdx.y * 128;

    f32x4 acc[4][4];
    #pragma unroll
    for (int i = 0; i < 4; ++i)
        #pragma unroll
        for (int j = 0; j < 4; ++j) acc[i][j] = (f32x4){0.f, 0.f, 0.f, 0.f};

    for (int kt = 0; kt < EMB; kt += 32) {
        __syncthreads();
        #pragma unroll
        for (int u = 0; u < 4; ++u) {
            int i  = u * 256 + tid;
            int r  = i >> 3;
            int c4 = (i & 7) * 4;
            float4 av = *(const float4*)(A + (m0 + r) * EMB + kt + c4);
            float4 wv = *(const float4*)(W + (n0 + r) * EMB + kt + c4);
            short4 as, bs;
            as.x = f2bf(av.x); as.y = f2bf(av.y); as.z = f2bf(av.z); as.w = f2bf(av.w);
            bs.x = f2bf(wv.x); bs.y = f2bf(wv.y); bs.z = f2bf(wv.z); bs.w = f2bf(wv.w);
            *(short4*)&sA[r * LDA + c4] = as;
            *(short4*)&sB[r * LDA + c4] = bs;
        }
        __syncthreads();

        bf16x8 af[4], bfr[4];
        #pragma unroll
        for (int rt = 0; rt < 4; ++rt)
            af[rt] = *(const bf16x8*)&sA[(wm + rt * 16 + l16) * LDA + quad * 8];
        #pragma unroll
        for (int ct = 0; ct < 4; ++ct)
            bfr[ct] = *(const bf16x8*)&sB[(wn + ct * 16 + l16) * LDA + quad * 8];
        #pragma unroll
        for (int rt = 0; rt < 4; ++rt)
            #pragma unroll
            for (int ct = 0; ct < 4; ++ct)
                acc[rt][ct] = __builtin_amdgcn_mfma_f32_16x16x32_bf16(
                    af[rt], bfr[ct], acc[rt][ct], 0, 0, 0);
    }

    #pragma unroll
    for (int rt = 0; rt < 4; ++rt) {
        #pragma unroll
        for (int ct = 0; ct < 4; ++ct) {
            #pragma unroll
            for (int reg = 0; reg < 4; ++reg) {
                const long row = m0 + wm + rt * 16 + quad * 4 + reg;
                const long col = n0 + wn + ct * 16 + l16;
                const int bb = (int)(row >> 11), ss = (int)(row & (SEQ - 1));
                const int hh = (int)(col >> 6),  dd = (int)(col & (HD - 1));
                C[(((long)(bb * NH + hh)) << 17) + ((long)ss << 6) + dd] = acc[rt][ct][reg];
            }
        }
    }
}

__global__ __launch_bounds__(256)
void gemm_out_mfma(const float* __restrict__ A, const float* __restrict__ W,
                   float* __restrict__ C)
{
    __shared__ short sA[128 * LDA];
    __shared__ short sB[128 * LDA];

    const int tid  = threadIdx.x;
    const int wave = tid >> 6, lane = tid & 63;
    const int quad = lane >> 4, l16 = lane & 15;
    const int wm = (wave >> 1) * 64, wn = (wave & 1) * 64;
    const long m0 = (long)blockIdx.x * 128, n0 = (long)blockIdx.y * 128;

    f32x4 acc[4][4];
    #pragma unroll
    for (int i = 0; i < 4; ++i)
        #pragma unroll
        for (int j = 0; j < 4; ++j) acc[i][j] = (f32x4){0.f, 0.f, 0.f, 0.f};

    for (int kt = 0; kt < DATTN; kt += 32) {
        __syncthreads();
        #pragma unroll
        for (int u = 0; u < 4; ++u) {
            int i  = u * 256 + tid;
            int r  = i >> 3;
            int c4 = (i & 7) * 4;
            float4 av = *(const float4*)(A + (m0 + r) * DATTN + kt + c4);
            float4 wv = *(const float4*)(W + (n0 + r) * DATTN + kt + c4);
            short4 as, bs;
            as.x = f2bf(av.x); as.y = f2bf(av.y); as.z = f2bf(av.z); as.w = f2bf(av.w);
            bs.x = f2bf(wv.x); bs.y = f2bf(wv.y); bs.z = f2bf(wv.z); bs.w = f2bf(wv.w);
            *(short4*)&sA[r * LDA + c4] = as;
            *(short4*)&sB[r * LDA + c4] = bs;
        }
        __syncthreads();

        bf16x8 af[4], bfr[4];
        #pragma unroll
        for (int rt = 0; rt < 4; ++rt)
            af[rt] = *(const bf16x8*)&sA[(wm + rt * 16 + l16) * LDA + quad * 8];
        #pragma unroll
        for (int ct = 0; ct < 4; ++ct)
            bfr[ct] = *(const bf16x8*)&sB[(wn + ct * 16 + l16) * LDA + quad * 8];
        #pragma unroll
        for (int rt = 0; rt < 4; ++rt)
            #pragma unroll
            for (int ct = 0; ct < 4; ++ct)
                acc[rt][ct] = __builtin_amdgcn_mfma_f32_16x16x32_bf16(
                    af[rt], bfr[ct], acc[rt][ct], 0, 0, 0);
    }

    #pragma unroll
    for (int rt = 0; rt < 4; ++rt) {
        #pragma unroll
        for (int ct = 0; ct < 4; ++ct) {
            #pragma unroll
            for (int reg = 0; reg < 4; ++reg) {
                const long row = m0 + wm + rt * 16 + quad * 4 + reg;
                const long col = n0 + wn + ct * 16 + l16;
                C[row * EMB + col] = acc[rt][ct][reg];
            }
        }
    }
}

// ---------------- RoPE (in-place on head-layout tensor [B,H,S,HD]) ----------------
__global__ void rope_kernel(float* __restrict__ X)
{
    const int t = blockIdx.x * blockDim.x + threadIdx.x;
    if (t >= BATCH * NH * SEQ * (HD / 2)) return;
    const int p  = t & 31;
    const int s  = (t >> 5) & (SEQ - 1);
    const int bh = t >> 16;
    const long base = (((long)bh * SEQ + s) << 6) + p * 2;
    const float inv_freq = powf(10000.0f, -(float)(2 * p) / 64.0f);
    const float ang = (float)s * inv_freq;
    float c, sn;
    __sincosf(ang, &sn, &c);
    const float x0 = X[base], x1 = X[base + 1];
    X[base]     = x0 * c - x1 * sn;
    X[base + 1] = x0 * sn + x1 * c;
}

// ---------------- MFMA flash attention ----------------
// Block = (b, h, 64-query tile), 4 waves x 16 queries. Per 64-key tile:
//   K staged row-major bf16 [key][dim], V staged TRANSPOSED bf16 [dim][key]
//   (pitch 68 shorts: 8B-aligned rows, conflict-free 2-lanes/bank frag reads).
//   QK^T: 8 mfma/wave (A=Q frags in regs, B=K rows).  Scores in C-layout:
//   q = qbase+quad*4+reg, key = ct*16+l16.  Online softmax row-reduce via
//   shfl_xor over the 16 l16 lanes.  P -> per-wave LDS region (bf16,
//   C-layout scatter), read back as A-frags (m120 round-trip), PV: 8 mfma
//   with V^T rows as B.  mask: j < i, except (0,0) allowed.
#define LDP 68

__global__ __launch_bounds__(256, 1)
void flash_attn_mfma(const float* __restrict__ Qh,
                     const float* __restrict__ Kh,
                     const float* __restrict__ Vh,
                     float* __restrict__ ctx)
{
    const int nt = SEQ / 64;                 // 32 query tiles
    const int t  = nt - 1 - blockIdx.x;      // heavy tiles dispatched first
    const int h  = blockIdx.y, b = blockIdx.z;
    const int tid = threadIdx.x;
    const int wave = tid >> 6, lane = tid & 63;
    const int quad = lane >> 4, l16 = lane & 15;
    const int r0 = t * 64;
    const int qbase = r0 + wave * 16;

    __shared__ short sk[64 * LDP];
    __shared__ short sv[64 * LDP];
    __shared__ short sp[4][16 * LDP];

    const long base = ((long)(b * NH + h)) * SEQ * HD;

    // Q fragments (A operand), pre-scaled, loaded once
    bf16x8 qf[2];
    {
        const float* qsrc = Qh + base + (long)(qbase + l16) * HD + quad * 8;
        #pragma unroll
        for (int tt = 0; tt < 2; ++tt) {
            float4 a = *(const float4*)(qsrc + tt * 32);
            float4 c = *(const float4*)(qsrc + tt * 32 + 4);
            qf[tt][0] = f2bf(a.x * SCALE); qf[tt][1] = f2bf(a.y * SCALE);
            qf[tt][2] = f2bf(a.z * SCALE); qf[tt][3] = f2bf(a.w * SCALE);
            qf[tt][4] = f2bf(c.x * SCALE); qf[tt][5] = f2bf(c.y * SCALE);
            qf[tt][6] = f2bf(c.z * SCALE); qf[tt][7] = f2bf(c.w * SCALE);
        }
    }

    f32x4 acc_o[4];
    #pragma unroll
    for (int ct = 0; ct < 4; ++ct) acc_o[ct] = (f32x4){0.f, 0.f, 0.f, 0.f};
    float mrow[4] = {MINIT, MINIT, MINIT, MINIT};
    float lrow[4] = {0.f, 0.f, 0.f, 0.f};

    const int njt = t + 1;

    #pragma unroll 1
    for (int jt = 0; jt < njt; ++jt) {
        const int jbase = jt * 64;

        __syncthreads();   // protect previous-iteration sk/sv reads
        // stage K row-major [key][dim]: thread -> key=tid>>2, 16-dim group
        {
            const int key = tid >> 2, dg = tid & 3;
            const float* src = Kh + base + (long)(jbase + key) * HD + dg * 16;
            short* dst = &sk[key * LDP + dg * 16];
            #pragma unroll
            for (int u = 0; u < 4; ++u) {
                float4 v4 = *(const float4*)(src + 4 * u);
                short4 s4;
                s4.x = f2bf(v4.x); s4.y = f2bf(v4.y);
                s4.z = f2bf(v4.z); s4.w = f2bf(v4.w);
                *(short4*)(dst + 4 * u) = s4;
            }
        }
        // stage V transposed [dim][key]: lane=key, wave picks 16 dims
        // (per-inst: wave-uniform row, lanes write consecutive shorts -> conflict-free)
        {
            const float* src = Vh + base + (long)(jbase + lane) * HD + wave * 16;
            #pragma unroll
            for (int u = 0; u < 4; ++u) {
                float4 v4 = *(const float4*)(src + 4 * u);
                sv[(wave * 16 + 4 * u + 0) * LDP + lane] = f2bf(v4.x);
                sv[(wave * 16 + 4 * u + 1) * LDP + lane] = f2bf(v4.y);
                sv[(wave * 16 + 4 * u + 2) * LDP + lane] = f2bf(v4.z);
                sv[(wave * 16 + 4 * u + 3) * LDP + lane] = f2bf(v4.w);
            }
        }
        __syncthreads();

        // QK^T: scores S[16q x 64k] per wave, C-layout
        f32x4 s[4];
        #pragma unroll
        for (int ct = 0; ct < 4; ++ct) {
            bf16x8 k0 = ld_frag(&sk[(ct * 16 + l16) * LDP + quad * 8]);
            bf16x8 k1 = ld_frag(&sk[(ct * 16 + l16) * LDP + 32 + quad * 8]);
            f32x4 z = (f32x4){0.f, 0.f, 0.f, 0.f};
            z = __builtin_amdgcn_mfma_f32_16x16x32_bf16(qf[0], k0, z, 0, 0, 0);
            z = __builtin_amdgcn_mfma_f32_16x16x32_bf16(qf[1], k1, z, 0, 0, 0);
            s[ct] = z;
        }

        // causal mask — only the last key tile can violate j < i
        if (jt == t) {
            #pragma unroll
            for (int ct = 0; ct < 4; ++ct) {
                const int j = jbase + ct * 16 + l16;
                #pragma unroll
                for (int r = 0; r < 4; ++r) {
                    const int i = qbase + quad * 4 + r;
                    const bool ok = (j < i) || (i == 0 && j == 0);
                    if (!ok) s[ct][r] = -INFINITY;
                }
            }
        }

        // online softmax per row (row stats live redundantly in all 16 l16 lanes)
        float alpha[4];
        #pragma unroll
        for (int r = 0; r < 4; ++r) {
            float mx = fmaxf(fmaxf(s[0][r], s[1][r]), fmaxf(s[2][r], s[3][r]));
            mx = fmaxf(mx, __shfl_xor(mx, 1, 64));
            mx = fmaxf(mx, __shfl_xor(mx, 2, 64));
            mx = fmaxf(mx, __shfl_xor(mx, 4, 64));
            mx = fmaxf(mx, __shfl_xor(mx, 8, 64));
            const float mn = fmaxf(mrow[r], mx);
            alpha[r] = __expf(mrow[r] - mn);
            mrow[r] = mn;
            float e0 = __expf(s[0][r] - mn);
            float e1 = __expf(s[1][r] - mn);
            float e2 = __expf(s[2][r] - mn);
            float e3 = __expf(s[3][r] - mn);
            s[0][r] = e0; s[1][r] = e1; s[2][r] = e2; s[3][r] = e3;
            float ss = (e0 + e1) + (e2 + e3);
            ss += __shfl_xor(ss, 1, 64);
            ss += __shfl_xor(ss, 2, 64);
            ss += __shfl_xor(ss, 4, 64);
            ss += __shfl_xor(ss, 8, 64);
            lrow[r] = lrow[r] * alpha[r] + ss;
        }

        // write P (bf16) to this wave's LDS region, C-layout scatter
        short* pw = sp[wave];
        #pragma unroll
        for (int ct = 0; ct < 4; ++ct)
            #pragma unroll
            for (int r = 0; r < 4; ++r)
                pw[(quad * 4 + r) * LDP + ct * 16 + l16] = f2bf(s[ct][r]);

        // rescale accumulator
        #pragma unroll
        for (int ct = 0; ct < 4; ++ct)
            #pragma unroll
            for (int r = 0; r < 4; ++r)
                acc_o[ct][r] *= alpha[r];

        // PV: read P back as A-frags (same-wave write->read; compiler inserts lgkmcnt)
        bf16x8 pf0 = ld_frag(&pw[l16 * LDP + quad * 8]);
        bf16x8 pf1 = ld_frag(&pw[l16 * LDP + 32 + quad * 8]);
        #pragma unroll
        for (int ct = 0; ct < 4; ++ct) {
            bf16x8 v0 = ld_frag(&sv[(ct * 16 + l16) * LDP + quad * 8]);
            bf16x8 v1 = ld_frag(&sv[(ct * 16 + l16) * LDP + 32 + quad * 8]);
            acc_o[ct] = __builtin_amdgcn_mfma_f32_16x16x32_bf16(pf0, v0, acc_o[ct], 0, 0, 0);
            acc_o[ct] = __builtin_amdgcn_mfma_f32_16x16x32_bf16(pf1, v1, acc_o[ct], 0, 0, 0);
        }
    }

    // epilogue: ctx layout [B, S, DATTN]
    #pragma unroll
    for (int r = 0; r < 4; ++r) {
        const float inv = 1.f / lrow[r];
        const int i = qbase + quad * 4 + r;
        float* o = ctx + ((long)(b * SEQ + i)) * DATTN + h * HD + l16;
        #pragma unroll
        for (int ct = 0; ct < 4; ++ct)
            o[ct * 16] = acc_o[ct][r] * inv;
    }
}

extern "C" void kernel_launch(void* const* d_in, const int* in_sizes, int n_in,
                              void* d_out, int out_size, void* d_ws, size_t ws_size,
                              hipStream_t stream) {
    const float* q  = (const float*)d_in[0];
    const float* k  = (const float*)d_in[1];
    const float* v  = (const float*)d_in[2];
    const float* Wq = (const float*)d_in[3];
    const float* Wk = (const float*)d_in[4];
    const float* Wv = (const float*)d_in[5];
    const float* Wo = (const float*)d_in[6];
    float* out = (float*)d_out;

    // workspace layout (fp32): Qh | Kh | Vh | ctx  — 4 x 16 MB = 64 MB
    const long TSZ = (long)BATCH * NH * SEQ * HD;   // 4,194,304
    float* Qh  = (float*)d_ws;
    float* Kh  = Qh + TSZ;
    float* Vh  = Kh + TSZ;
    float* ctx = Vh + TSZ;

    gemm_proj_mfma<<<dim3(MM / 128, DATTN / 128, 3), 256, 0, stream>>>(
        q, k, v, Wq, Wk, Wv, Qh, Kh, Vh);

    const int npairs = BATCH * NH * SEQ * (HD / 2);  // 2,097,152
    rope_kernel<<<(npairs + 255) / 256, 256, 0, stream>>>(Qh);
    rope_kernel<<<(npairs + 255) / 256, 256, 0, stream>>>(Kh);

    flash_attn_mfma<<<dim3(SEQ / 64, NH, BATCH), 256, 0, stream>>>(Qh, Kh, Vh, ctx);

    gemm_out_mfma<<<dim3(MM / 128, EMB / 128), 256, 0, stream>>>(ctx, Wo, out);
}

// Round 9
// 289.716 us; speedup vs baseline: 25.9119x; 1.3379x over previous
//
#include <hip/hip_runtime.h>
#include <hip/hip_bf16.h>

// Problem constants (fixed shapes)
#define BATCH 2
#define SEQ   2048
#define EMB   1024
#define DATTN 1024
#define NH    16
#define HD    64
#define MM    (BATCH*SEQ)        // 4096 rows
#define SCALE 0.03125f           // 1/sqrt(1024), exact power of 2
#define MINIT -1.0e30f

using bf16x8 = __attribute__((ext_vector_type(8))) short;   // 8 bf16 (4 VGPRs)
using f32x4  = __attribute__((ext_vector_type(4))) float;   // MFMA C/D

__device__ inline short f2bf(float x) {
    __hip_bfloat16 b = __float2bfloat16(x);
    return *reinterpret_cast<short*>(&b);
}
__device__ inline float bf2f(unsigned int u16) {
    union { unsigned int i; float f; } c;
    c.i = u16 << 16;
    return c.f;
}

// ---------------- MFMA GEMM tiles: 128x128 block, 4 waves (2x2 of 64x64) ----------------
#define LDA 40

// Fused Q/K/V projection. Outputs bf16:
//   z=0: Qb head-layout [B,H,S,HD], pre-scaled by SCALE
//   z=1: Kb head-layout [B,H,S,HD]
//   z=2: Vtb TRANSPOSED [B,H,HD,S]
__global__ __launch_bounds__(256)
void gemm_proj_mfma(const float* __restrict__ q, const float* __restrict__ k,
                    const float* __restrict__ v,
                    const float* __restrict__ Wq, const float* __restrict__ Wk,
                    const float* __restrict__ Wv,
                    short* __restrict__ Qb, short* __restrict__ Kb,
                    short* __restrict__ Vtb)
{
    const float* A; const float* W;
    if (blockIdx.z == 0)      { A = q; W = Wq; }
    else if (blockIdx.z == 1) { A = k; W = Wk; }
    else                      { A = v; W = Wv; }

    __shared__ short sA[128 * LDA];
    __shared__ short sB[128 * LDA];

    const int tid  = threadIdx.x;
    const int wave = tid >> 6, lane = tid & 63;
    const int quad = lane >> 4, l16 = lane & 15;
    const int wm = (wave >> 1) * 64, wn = (wave & 1) * 64;
    const long m0 = (long)blockIdx.x * 128, n0 = (long)blockIdx.y * 128;

    f32x4 acc[4][4];
    #pragma unroll
    for (int i = 0; i < 4; ++i)
        #pragma unroll
        for (int j = 0; j < 4; ++j) acc[i][j] = (f32x4){0.f, 0.f, 0.f, 0.f};

    for (int kt = 0; kt < EMB; kt += 32) {
        __syncthreads();
        #pragma unroll
        for (int u = 0; u < 4; ++u) {
            int i  = u * 256 + tid;
            int r  = i >> 3;
            int c4 = (i & 7) * 4;
            float4 av = *(const float4*)(A + (m0 + r) * EMB + kt + c4);
            float4 wv = *(const float4*)(W + (n0 + r) * EMB + kt + c4);
            short4 as, bs;
            as.x = f2bf(av.x); as.y = f2bf(av.y); as.z = f2bf(av.z); as.w = f2bf(av.w);
            bs.x = f2bf(wv.x); bs.y = f2bf(wv.y); bs.z = f2bf(wv.z); bs.w = f2bf(wv.w);
            *(short4*)&sA[r * LDA + c4] = as;
            *(short4*)&sB[r * LDA + c4] = bs;
        }
        __syncthreads();

        bf16x8 af[4], bfr[4];
        #pragma unroll
        for (int rt = 0; rt < 4; ++rt)
            af[rt] = *(const bf16x8*)&sA[(wm + rt * 16 + l16) * LDA + quad * 8];
        #pragma unroll
        for (int ct = 0; ct < 4; ++ct)
            bfr[ct] = *(const bf16x8*)&sB[(wn + ct * 16 + l16) * LDA + quad * 8];
        #pragma unroll
        for (int rt = 0; rt < 4; ++rt)
            #pragma unroll
            for (int ct = 0; ct < 4; ++ct)
                acc[rt][ct] = __builtin_amdgcn_mfma_f32_16x16x32_bf16(
                    af[rt], bfr[ct], acc[rt][ct], 0, 0, 0);
    }

    if (blockIdx.z < 2) {
        short* C = (blockIdx.z == 0) ? Qb : Kb;
        const float scl = (blockIdx.z == 0) ? SCALE : 1.0f;
        #pragma unroll
        for (int rt = 0; rt < 4; ++rt) {
            #pragma unroll
            for (int ct = 0; ct < 4; ++ct) {
                #pragma unroll
                for (int reg = 0; reg < 4; ++reg) {
                    const long row = m0 + wm + rt * 16 + quad * 4 + reg;
                    const long col = n0 + wn + ct * 16 + l16;
                    const int bb = (int)(row >> 11), ss = (int)(row & (SEQ - 1));
                    const int hh = (int)(col >> 6),  dd = (int)(col & (HD - 1));
                    C[(((long)(bb * NH + hh)) << 17) + ((long)ss << 6) + dd] =
                        f2bf(acc[rt][ct][reg] * scl);
                }
            }
        }
    } else {
        // V transposed: Vt[((b*NH+h)*HD + d)*SEQ + s]; 4 regs = 4 consecutive s
        #pragma unroll
        for (int rt = 0; rt < 4; ++rt) {
            #pragma unroll
            for (int ct = 0; ct < 4; ++ct) {
                const long row0 = m0 + wm + rt * 16 + quad * 4;
                const long col  = n0 + wn + ct * 16 + l16;
                const int bb = (int)(row0 >> 11), ss = (int)(row0 & (SEQ - 1));
                const int hh = (int)(col >> 6),   dd = (int)(col & (HD - 1));
                short4 s4;
                s4.x = f2bf(acc[rt][ct][0]); s4.y = f2bf(acc[rt][ct][1]);
                s4.z = f2bf(acc[rt][ct][2]); s4.w = f2bf(acc[rt][ct][3]);
                *(short4*)&Vtb[(((long)(bb * NH + hh)) << 17) + ((long)dd << 11) + ss] = s4;
            }
        }
    }
}

// Output GEMM: out = ctx(bf16) @ Wo^T(fp32), out fp32 [4096,1024]
__global__ __launch_bounds__(256)
void gemm_out_mfma(const short* __restrict__ Ab, const float* __restrict__ W,
                   float* __restrict__ C)
{
    __shared__ short sA[128 * LDA];
    __shared__ short sB[128 * LDA];

    const int tid  = threadIdx.x;
    const int wave = tid >> 6, lane = tid & 63;
    const int quad = lane >> 4, l16 = lane & 15;
    const int wm = (wave >> 1) * 64, wn = (wave & 1) * 64;
    const long m0 = (long)blockIdx.x * 128, n0 = (long)blockIdx.y * 128;

    f32x4 acc[4][4];
    #pragma unroll
    for (int i = 0; i < 4; ++i)
        #pragma unroll
        for (int j = 0; j < 4; ++j) acc[i][j] = (f32x4){0.f, 0.f, 0.f, 0.f};

    for (int kt = 0; kt < DATTN; kt += 32) {
        __syncthreads();
        // A: pure bf16 copy (2 x 16B chunks per thread)
        #pragma unroll
        for (int c = 0; c < 2; ++c) {
            int cc  = c * 256 + tid;       // 0..511
            int row = cc >> 2;
            int off = (cc & 3) * 8;
            int4 tA = *(const int4*)(Ab + (m0 + row) * DATTN + kt + off);
            *(int4*)&sA[row * LDA + off] = tA;
        }
        // B: fp32 -> bf16 convert
        #pragma unroll
        for (int u = 0; u < 4; ++u) {
            int i  = u * 256 + tid;
            int r  = i >> 3;
            int c4 = (i & 7) * 4;
            float4 wv = *(const float4*)(W + (n0 + r) * DATTN + kt + c4);
            short4 bs;
            bs.x = f2bf(wv.x); bs.y = f2bf(wv.y); bs.z = f2bf(wv.z); bs.w = f2bf(wv.w);
            *(short4*)&sB[r * LDA + c4] = bs;
        }
        __syncthreads();

        bf16x8 af[4], bfr[4];
        #pragma unroll
        for (int rt = 0; rt < 4; ++rt)
            af[rt] = *(const bf16x8*)&sA[(wm + rt * 16 + l16) * LDA + quad * 8];
        #pragma unroll
        for (int ct = 0; ct < 4; ++ct)
            bfr[ct] = *(const bf16x8*)&sB[(wn + ct * 16 + l16) * LDA + quad * 8];
        #pragma unroll
        for (int rt = 0; rt < 4; ++rt)
            #pragma unroll
            for (int ct = 0; ct < 4; ++ct)
                acc[rt][ct] = __builtin_amdgcn_mfma_f32_16x16x32_bf16(
                    af[rt], bfr[ct], acc[rt][ct], 0, 0, 0);
    }

    #pragma unroll
    for (int rt = 0; rt < 4; ++rt) {
        #pragma unroll
        for (int ct = 0; ct < 4; ++ct) {
            #pragma unroll
            for (int reg = 0; reg < 4; ++reg) {
                const long row = m0 + wm + rt * 16 + quad * 4 + reg;
                const long col = n0 + wn + ct * 16 + l16;
                C[row * EMB + col] = acc[rt][ct][reg];
            }
        }
    }
}

// ---------------- RoPE in-place on bf16 head-layout tensor [B,H,S,HD] ----------------
__global__ void rope_bf16(unsigned short* __restrict__ X)
{
    const int t = blockIdx.x * blockDim.x + threadIdx.x;
    if (t >= BATCH * NH * SEQ * (HD / 2)) return;
    const int p  = t & 31;
    const int s  = (t >> 5) & (SEQ - 1);
    const int bh = t >> 16;
    const long base = (((long)bh * SEQ + s) << 6) + 2 * p;
    unsigned int u = *(unsigned int*)&X[base];
    const float x0 = bf2f(u & 0xFFFFu);
    const float x1 = bf2f(u >> 16);
    const float inv_freq = powf(10000.0f, -(float)(2 * p) / 64.0f);
    const float ang = (float)s * inv_freq;
    float c, sn;
    __sincosf(ang, &sn, &c);
    const float o0 = x0 * c - x1 * sn;
    const float o1 = x0 * sn + x1 * c;
    unsigned int outp = (unsigned int)(unsigned short)f2bf(o0)
                      | ((unsigned int)(unsigned short)f2bf(o1) << 16);
    *(unsigned int*)&X[base] = outp;
}

// ---------------- MFMA flash attention (S^T formulation) ----------------
// Block = (b, h, 128-query tile), 4 waves. Wave handles 2 groups of 16 queries
// (rows r0+64g+wave*16 .. +16). All inputs pre-converted bf16; Q pre-scaled.
// Per 64-key tile: sk = K [key][dim], sv = Vt tile [dim][key], pitch 72
// (144B rows: 16B-aligned b128 frags, even bank spread).
// S^T = mfma(A=K, B=Q): C-layout col=l16=query, row=quad*4+reg=key ->
// softmax state is scalar per lane (2 shfl over quad bits). P stored
// row-major [query][key] via 4 ds_write_b64, read back as B-frag.
// PV = mfma(A=Vt, B=P): C row=dim, col=query. mask: j<i, (0,0) allowed.
#define LDP 72

__global__ __launch_bounds__(256, 1)
void flash_attn_mfma(const short* __restrict__ Qb,
                     const short* __restrict__ Kb,
                     const short* __restrict__ Vtb,
                     short* __restrict__ ctx)
{
    const int t  = (SEQ / 128) - 1 - blockIdx.x;   // heavy tiles first
    const int h  = blockIdx.y, b = blockIdx.z;
    const int tid = threadIdx.x;
    const int wave = tid >> 6, lane = tid & 63;
    const int quad = lane >> 4, l16 = lane & 15;
    const int r0 = t * 128;

    __shared__ short sk[64 * LDP];
    __shared__ short sv[64 * LDP];
    __shared__ short sp[4][16 * LDP];

    const long base = ((long)(b * NH + h)) << 17;   // SEQ*HD = 2^17

    // Q fragments (B operand): row l16 = query, k = quad*8 (+tt*32)
    bf16x8 qf[2][2];
    #pragma unroll
    for (int g = 0; g < 2; ++g)
        #pragma unroll
        for (int tt = 0; tt < 2; ++tt)
            qf[g][tt] = *(const bf16x8*)(Qb + base
                + (long)(r0 + 64 * g + wave * 16 + l16) * HD + tt * 32 + quad * 8);

    f32x4 acc_o[2][4];
    #pragma unroll
    for (int g = 0; g < 2; ++g)
        #pragma unroll
        for (int ct = 0; ct < 4; ++ct) acc_o[g][ct] = (f32x4){0.f, 0.f, 0.f, 0.f};
    float mq[2] = {MINIT, MINIT};
    float lq[2] = {0.f, 0.f};

    const int njt = 2 * t + 2;

    #pragma unroll 1
    for (int jt = 0; jt < njt; ++jt) {
        const int jbase = jt * 64;

        __syncthreads();   // protect previous-iteration sk/sv reads
        #pragma unroll
        for (int c = 0; c < 2; ++c) {
            int cc  = c * 256 + tid;          // 0..511
            int row = cc >> 3;                // 0..63
            int off = (cc & 7) * 8;           // 0..56
            int4 tK = *(const int4*)(Kb + base + (long)(jbase + row) * HD + off);
            *(int4*)&sk[row * LDP + off] = tK;
            int4 tV = *(const int4*)(Vtb + base + ((long)row << 11) + jbase + off);
            *(int4*)&sv[row * LDP + off] = tV;
        }
        __syncthreads();

        // K frags (A op: row l16 = key) and Vt frags (A op: row l16 = dim), shared by g
        bf16x8 kf[4][2], vf[4][2];
        #pragma unroll
        for (int ct = 0; ct < 4; ++ct) {
            kf[ct][0] = *(const bf16x8*)&sk[(ct * 16 + l16) * LDP + quad * 8];
            kf[ct][1] = *(const bf16x8*)&sk[(ct * 16 + l16) * LDP + 32 + quad * 8];
            vf[ct][0] = *(const bf16x8*)&sv[(ct * 16 + l16) * LDP + quad * 8];
            vf[ct][1] = *(const bf16x8*)&sv[(ct * 16 + l16) * LDP + 32 + quad * 8];
        }

        short* pw = sp[wave];

        #pragma unroll
        for (int g = 0; g < 2; ++g) {
            if (g == 0 && jt == 2 * t + 1) continue;   // g0 fully masked on last tile

            // S^T: 8 mfma; C-layout: col=l16=query, row=quad*4+reg=key (in ct-th 16-key tile)
            f32x4 s[4];
            #pragma unroll
            for (int ct = 0; ct < 4; ++ct) {
                f32x4 z = (f32x4){0.f, 0.f, 0.f, 0.f};
                z = __builtin_amdgcn_mfma_f32_16x16x32_bf16(kf[ct][0], qf[g][0], z, 0, 0, 0);
                z = __builtin_amdgcn_mfma_f32_16x16x32_bf16(kf[ct][1], qf[g][1], z, 0, 0, 0);
                s[ct] = z;
            }

            const int iq = r0 + 64 * g + wave * 16 + l16;   // this lane's query
            if (jt == 2 * t + g) {   // only tile that can violate j < i for this group
                #pragma unroll
                for (int ct = 0; ct < 4; ++ct)
                    #pragma unroll
                    for (int r = 0; r < 4; ++r) {
                        const int j = jbase + ct * 16 + quad * 4 + r;
                        const bool ok = (j < iq) || (iq == 0 && j == 0);
                        if (!ok) s[ct][r] = -INFINITY;
                    }
            }

            // online softmax: per-lane query state; reduce over quad bits (16,32)
            float mx = MINIT;
            #pragma unroll
            for (int ct = 0; ct < 4; ++ct)
                #pragma unroll
                for (int r = 0; r < 4; ++r) mx = fmaxf(mx, s[ct][r]);
            mx = fmaxf(mx, __shfl_xor(mx, 16, 64));
            mx = fmaxf(mx, __shfl_xor(mx, 32, 64));
            const float mn = fmaxf(mq[g], mx);
            const float alpha = __expf(mq[g] - mn);
            mq[g] = mn;
            float ss = 0.f;
            #pragma unroll
            for (int ct = 0; ct < 4; ++ct)
                #pragma unroll
                for (int r = 0; r < 4; ++r) {
                    const float e = __expf(s[ct][r] - mn);
                    s[ct][r] = e;
                    ss += e;
                }
            ss += __shfl_xor(ss, 16, 64);
            ss += __shfl_xor(ss, 32, 64);
            lq[g] = lq[g] * alpha + ss;

            // P -> LDS row-major [query][key]: 4 x ds_write_b64 (keys quad*4+r consecutive)
            #pragma unroll
            for (int ct = 0; ct < 4; ++ct) {
                short4 p4;
                p4.x = f2bf(s[ct][0]); p4.y = f2bf(s[ct][1]);
                p4.z = f2bf(s[ct][2]); p4.w = f2bf(s[ct][3]);
                *(short4*)&pw[l16 * LDP + ct * 16 + quad * 4] = p4;
            }

            #pragma unroll
            for (int ct = 0; ct < 4; ++ct)
                #pragma unroll
                for (int r = 0; r < 4; ++r) acc_o[g][ct][r] *= alpha;

            // P frags (B op: row l16 = query, k = key). Same-wave LDS write->read,
            // in-order DS pipe makes the g0->g1 region reuse safe.
            bf16x8 pf0 = *(const bf16x8*)&pw[l16 * LDP + quad * 8];
            bf16x8 pf1 = *(const bf16x8*)&pw[l16 * LDP + 32 + quad * 8];
            #pragma unroll
            for (int ct = 0; ct < 4; ++ct) {
                acc_o[g][ct] = __builtin_amdgcn_mfma_f32_16x16x32_bf16(
                    vf[ct][0], pf0, acc_o[g][ct], 0, 0, 0);
                acc_o[g][ct] = __builtin_amdgcn_mfma_f32_16x16x32_bf16(
                    vf[ct][1], pf1, acc_o[g][ct], 0, 0, 0);
            }
        }
    }

    // epilogue: acc_o C-layout row=dim (ct*16+quad*4+reg), col=l16=query.
    // ctx bf16 [B,S,DATTN]; 4 consecutive dims -> short4 store.
    #pragma unroll
    for (int g = 0; g < 2; ++g) {
        const float inv = 1.f / lq[g];
        const int iq = r0 + 64 * g + wave * 16 + l16;
        short* orow = ctx + (long)(b * SEQ + iq) * DATTN + h * HD;
        #pragma unroll
        for (int ct = 0; ct < 4; ++ct) {
            short4 o4;
            o4.x = f2bf(acc_o[g][ct][0] * inv);
            o4.y = f2bf(acc_o[g][ct][1] * inv);
            o4.z = f2bf(acc_o[g][ct][2] * inv);
            o4.w = f2bf(acc_o[g][ct][3] * inv);
            *(short4*)&orow[ct * 16 + quad * 4] = o4;
        }
    }
}

extern "C" void kernel_launch(void* const* d_in, const int* in_sizes, int n_in,
                              void* d_out, int out_size, void* d_ws, size_t ws_size,
                              hipStream_t stream) {
    const float* q  = (const float*)d_in[0];
    const float* k  = (const float*)d_in[1];
    const float* v  = (const float*)d_in[2];
    const float* Wq = (const float*)d_in[3];
    const float* Wk = (const float*)d_in[4];
    const float* Wv = (const float*)d_in[5];
    const float* Wo = (const float*)d_in[6];
    float* out = (float*)d_out;

    // workspace (bf16): Qb | Kb | Vtb | ctx  — 4 x 8 MB = 32 MB
    const long TSZ = (long)BATCH * NH * SEQ * HD;   // 4,194,304
    short* Qb  = (short*)d_ws;
    short* Kb  = Qb + TSZ;
    short* Vtb = Kb + TSZ;
    short* ctx = Vtb + TSZ;

    gemm_proj_mfma<<<dim3(MM / 128, DATTN / 128, 3), 256, 0, stream>>>(
        q, k, v, Wq, Wk, Wv, Qb, Kb, Vtb);

    const int npairs = BATCH * NH * SEQ * (HD / 2);  // 2,097,152
    rope_bf16<<<(npairs + 255) / 256, 256, 0, stream>>>((unsigned short*)Qb);
    rope_bf16<<<(npairs + 255) / 256, 256, 0, stream>>>((unsigned short*)Kb);

    flash_attn_mfma<<<dim3(SEQ / 128, NH, BATCH), 256, 0, stream>>>(Qb, Kb, Vtb, ctx);

    gemm_out_mfma<<<dim3(MM / 128, EMB / 128), 256, 0, stream>>>(ctx, Wo, out);
}

// Round 10
// 265.161 us; speedup vs baseline: 28.3114x; 1.0926x over previous
//
#include <hip/hip_runtime.h>
#include <hip/hip_bf16.h>

// Problem constants (fixed shapes)
#define BATCH 2
#define SEQ   2048
#define EMB   1024
#define DATTN 1024
#define NH    16
#define HD    64
#define MM    (BATCH*SEQ)        // 4096 rows
#define SCALE 0.03125f           // 1/sqrt(1024), exact power of 2
#define MINIT -1.0e30f

using bf16x8 = __attribute__((ext_vector_type(8))) short;   // 8 bf16 (4 VGPRs)
using f32x4  = __attribute__((ext_vector_type(4))) float;   // MFMA C/D

__device__ inline short f2bf(float x) {
    __hip_bfloat16 b = __float2bfloat16(x);
    return *reinterpret_cast<short*>(&b);
}
__device__ inline float bf2f(unsigned int u16) {
    union { unsigned int i; float f; } c;
    c.i = u16 << 16;
    return c.f;
}

// async global->LDS, 16 B per lane. LDS dst must be wave-uniform (HW scatters
// lane i to dst + i*16); global src is per-lane. [m03/m97]
__device__ inline void gl_lds16(const short* g, short* l) {
    __builtin_amdgcn_global_load_lds(
        (const __attribute__((address_space(1))) unsigned int*)g,
        (__attribute__((address_space(3))) unsigned int*)l, 16, 0, 0);
}

// ---------------- fp32 -> bf16 pre-convert (q,k,v,Wq,Wk,Wv,Wo) ----------------
// dst is one contiguous bf16 region: qb|kb|vb (4M each) then wqb|wkb|wvb|wob (1M each)
__global__ __launch_bounds__(256)
void cvt_all(const float* __restrict__ q, const float* __restrict__ k,
             const float* __restrict__ v,
             const float* __restrict__ Wq, const float* __restrict__ Wk,
             const float* __restrict__ Wv, const float* __restrict__ Wo,
             short* __restrict__ dst)
{
    const long QKV = (long)MM * EMB;      // 4,194,304
    const long WSZ = (long)DATTN * EMB;   // 1,048,576
    const long i = ((long)blockIdx.x * 256 + threadIdx.x) * 4;   // grid sized exactly
    const float* s;
    long off;
    if (i < 3 * QKV) {
        const int seg = (int)(i / QKV);
        off = i - (long)seg * QKV;
        s = (seg == 0) ? q : (seg == 1) ? k : v;
    } else {
        const long j = i - 3 * QKV;
        const int seg = (int)(j / WSZ);
        off = j - (long)seg * WSZ;
        s = (seg == 0) ? Wq : (seg == 1) ? Wk : (seg == 2) ? Wv : Wo;
    }
    float4 x = *(const float4*)(s + off);
    short4 y;
    y.x = f2bf(x.x); y.y = f2bf(x.y); y.z = f2bf(x.z); y.w = f2bf(x.w);
    *(short4*)(dst + i) = y;
}

// ---------------- bf16 MFMA GEMM: 128x128 tile, BK=32, global_load_lds staging ----------------
// LDS tiles unpadded (row = 32 shorts = 64 B) — required by global_load_lds's
// lane-contiguous scatter; frag-read bank pattern is balanced (8 dwords/bank).

// stage one 128x32-bf16 tile (8 KB): 2 insts/wave, rows w*32+q*16+(lane>>2), col (lane&3)*8
__device__ inline void stage_tile(const short* g, short* lds, int wave, int lane) {
    #pragma unroll
    for (int qq = 0; qq < 2; ++qq) {
        const int r = wave * 32 + qq * 16 + (lane >> 2);
        gl_lds16(g + (long)r * EMB + (lane & 3) * 8, lds + (wave * 2 + qq) * 512);
    }
}

// Fused Q/K/V projection. Outputs bf16:
//   z=0: Qb head-layout [B,H,S,HD], pre-scaled by SCALE
//   z=1: Kb head-layout [B,H,S,HD]
//   z=2: Vtb TRANSPOSED [B,H,HD,S]
__global__ __launch_bounds__(256)
void gemm_proj_bf16(const short* __restrict__ qb, const short* __restrict__ kb,
                    const short* __restrict__ vb,
                    const short* __restrict__ wqb, const short* __restrict__ wkb,
                    const short* __restrict__ wvb,
                    short* __restrict__ Qb, short* __restrict__ Kb,
                    short* __restrict__ Vtb)
{
    const short* A; const short* B;
    if (blockIdx.z == 0)      { A = qb; B = wqb; }
    else if (blockIdx.z == 1) { A = kb; B = wkb; }
    else                      { A = vb; B = wvb; }

    __shared__ short sA[128 * 32];
    __shared__ short sB[128 * 32];

    const int tid  = threadIdx.x;
    const int wave = tid >> 6, lane = tid & 63;
    const int quad = lane >> 4, l16 = lane & 15;
    const int wm = (wave >> 1) * 64, wn = (wave & 1) * 64;
    const long m0 = (long)blockIdx.x * 128, n0 = (long)blockIdx.y * 128;

    f32x4 acc[4][4];
    #pragma unroll
    for (int i = 0; i < 4; ++i)
        #pragma unroll
        for (int j = 0; j < 4; ++j) acc[i][j] = (f32x4){0.f, 0.f, 0.f, 0.f};

    for (int kt = 0; kt < EMB; kt += 32) {
        __syncthreads();                       // prior frag reads done
        stage_tile(A + m0 * EMB + kt, sA, wave, lane);
        stage_tile(B + n0 * EMB + kt, sB, wave, lane);
        __syncthreads();                       // drains vmcnt -> staging visible

        bf16x8 af[4], bfr[4];
        #pragma unroll
        for (int rt = 0; rt < 4; ++rt)
            af[rt] = *(const bf16x8*)&sA[(wm + rt * 16 + l16) * 32 + quad * 8];
        #pragma unroll
        for (int ct = 0; ct < 4; ++ct)
            bfr[ct] = *(const bf16x8*)&sB[(wn + ct * 16 + l16) * 32 + quad * 8];
        #pragma unroll
        for (int rt = 0; rt < 4; ++rt)
            #pragma unroll
            for (int ct = 0; ct < 4; ++ct)
                acc[rt][ct] = __builtin_amdgcn_mfma_f32_16x16x32_bf16(
                    af[rt], bfr[ct], acc[rt][ct], 0, 0, 0);
    }

    if (blockIdx.z < 2) {
        short* C = (blockIdx.z == 0) ? Qb : Kb;
        const float scl = (blockIdx.z == 0) ? SCALE : 1.0f;
        #pragma unroll
        for (int rt = 0; rt < 4; ++rt) {
            #pragma unroll
            for (int ct = 0; ct < 4; ++ct) {
                #pragma unroll
                for (int reg = 0; reg < 4; ++reg) {
                    const long row = m0 + wm + rt * 16 + quad * 4 + reg;
                    const long col = n0 + wn + ct * 16 + l16;
                    const int bb = (int)(row >> 11), ss = (int)(row & (SEQ - 1));
                    const int hh = (int)(col >> 6),  dd = (int)(col & (HD - 1));
                    C[(((long)(bb * NH + hh)) << 17) + ((long)ss << 6) + dd] =
                        f2bf(acc[rt][ct][reg] * scl);
                }
            }
        }
    } else {
        // V transposed: Vt[((b*NH+h)*HD + d)*SEQ + s]; 4 regs = 4 consecutive s
        #pragma unroll
        for (int rt = 0; rt < 4; ++rt) {
            #pragma unroll
            for (int ct = 0; ct < 4; ++ct) {
                const long row0 = m0 + wm + rt * 16 + quad * 4;
                const long col  = n0 + wn + ct * 16 + l16;
                const int bb = (int)(row0 >> 11), ss = (int)(row0 & (SEQ - 1));
                const int hh = (int)(col >> 6),   dd = (int)(col & (HD - 1));
                short4 s4;
                s4.x = f2bf(acc[rt][ct][0]); s4.y = f2bf(acc[rt][ct][1]);
                s4.z = f2bf(acc[rt][ct][2]); s4.w = f2bf(acc[rt][ct][3]);
                *(short4*)&Vtb[(((long)(bb * NH + hh)) << 17) + ((long)dd << 11) + ss] = s4;
            }
        }
    }
}

// Output GEMM: out = ctx(bf16) @ Wo^T(bf16), out fp32 [4096,1024]
__global__ __launch_bounds__(256)
void gemm_out_bf16(const short* __restrict__ Ab, const short* __restrict__ Bb,
                   float* __restrict__ C)
{
    __shared__ short sA[128 * 32];
    __shared__ short sB[128 * 32];

    const int tid  = threadIdx.x;
    const int wave = tid >> 6, lane = tid & 63;
    const int quad = lane >> 4, l16 = lane & 15;
    const int wm = (wave >> 1) * 64, wn = (wave & 1) * 64;
    const long m0 = (long)blockIdx.x * 128, n0 = (long)blockIdx.y * 128;

    f32x4 acc[4][4];
    #pragma unroll
    for (int i = 0; i < 4; ++i)
        #pragma unroll
        for (int j = 0; j < 4; ++j) acc[i][j] = (f32x4){0.f, 0.f, 0.f, 0.f};

    for (int kt = 0; kt < DATTN; kt += 32) {
        __syncthreads();
        stage_tile(Ab + m0 * DATTN + kt, sA, wave, lane);
        stage_tile(Bb + n0 * DATTN + kt, sB, wave, lane);
        __syncthreads();

        bf16x8 af[4], bfr[4];
        #pragma unroll
        for (int rt = 0; rt < 4; ++rt)
            af[rt] = *(const bf16x8*)&sA[(wm + rt * 16 + l16) * 32 + quad * 8];
        #pragma unroll
        for (int ct = 0; ct < 4; ++ct)
            bfr[ct] = *(const bf16x8*)&sB[(wn + ct * 16 + l16) * 32 + quad * 8];
        #pragma unroll
        for (int rt = 0; rt < 4; ++rt)
            #pragma unroll
            for (int ct = 0; ct < 4; ++ct)
                acc[rt][ct] = __builtin_amdgcn_mfma_f32_16x16x32_bf16(
                    af[rt], bfr[ct], acc[rt][ct], 0, 0, 0);
    }

    #pragma unroll
    for (int rt = 0; rt < 4; ++rt) {
        #pragma unroll
        for (int ct = 0; ct < 4; ++ct) {
            #pragma unroll
            for (int reg = 0; reg < 4; ++reg) {
                const long row = m0 + wm + rt * 16 + quad * 4 + reg;
                const long col = n0 + wn + ct * 16 + l16;
                C[row * EMB + col] = acc[rt][ct][reg];
            }
        }
    }
}

// ---------------- RoPE in-place on bf16 head-layout [B,H,S,HD]; y: 0=Q, 1=K ----------------
__global__ void rope_bf16(unsigned short* __restrict__ Qb, unsigned short* __restrict__ Kb)
{
    unsigned short* X = blockIdx.y ? Kb : Qb;
    const int t = blockIdx.x * blockDim.x + threadIdx.x;
    const int p  = t & 31;
    const int s  = (t >> 5) & (SEQ - 1);
    const int bh = t >> 16;
    const long base = (((long)bh * SEQ + s) << 6) + 2 * p;
    unsigned int u = *(unsigned int*)&X[base];
    const float x0 = bf2f(u & 0xFFFFu);
    const float x1 = bf2f(u >> 16);
    const float inv_freq = powf(10000.0f, -(float)(2 * p) / 64.0f);
    const float ang = (float)s * inv_freq;
    float c, sn;
    __sincosf(ang, &sn, &c);
    const float o0 = x0 * c - x1 * sn;
    const float o1 = x0 * sn + x1 * c;
    unsigned int outp = (unsigned int)(unsigned short)f2bf(o0)
                      | ((unsigned int)(unsigned short)f2bf(o1) << 16);
    *(unsigned int*)&X[base] = outp;
}

// ---------------- MFMA flash attention (S^T formulation) — unchanged from R9 ----------------
#define LDP 72

__global__ __launch_bounds__(256, 1)
void flash_attn_mfma(const short* __restrict__ Qb,
                     const short* __restrict__ Kb,
                     const short* __restrict__ Vtb,
                     short* __restrict__ ctx)
{
    const int t  = (SEQ / 128) - 1 - blockIdx.x;   // heavy tiles first
    const int h  = blockIdx.y, b = blockIdx.z;
    const int tid = threadIdx.x;
    const int wave = tid >> 6, lane = tid & 63;
    const int quad = lane >> 4, l16 = lane & 15;
    const int r0 = t * 128;

    __shared__ short sk[64 * LDP];
    __shared__ short sv[64 * LDP];
    __shared__ short sp[4][16 * LDP];

    const long base = ((long)(b * NH + h)) << 17;   // SEQ*HD = 2^17

    bf16x8 qf[2][2];
    #pragma unroll
    for (int g = 0; g < 2; ++g)
        #pragma unroll
        for (int tt = 0; tt < 2; ++tt)
            qf[g][tt] = *(const bf16x8*)(Qb + base
                + (long)(r0 + 64 * g + wave * 16 + l16) * HD + tt * 32 + quad * 8);

    f32x4 acc_o[2][4];
    #pragma unroll
    for (int g = 0; g < 2; ++g)
        #pragma unroll
        for (int ct = 0; ct < 4; ++ct) acc_o[g][ct] = (f32x4){0.f, 0.f, 0.f, 0.f};
    float mq[2] = {MINIT, MINIT};
    float lq[2] = {0.f, 0.f};

    const int njt = 2 * t + 2;

    #pragma unroll 1
    for (int jt = 0; jt < njt; ++jt) {
        const int jbase = jt * 64;

        __syncthreads();
        #pragma unroll
        for (int c = 0; c < 2; ++c) {
            int cc  = c * 256 + tid;
            int row = cc >> 3;
            int off = (cc & 7) * 8;
            int4 tK = *(const int4*)(Kb + base + (long)(jbase + row) * HD + off);
            *(int4*)&sk[row * LDP + off] = tK;
            int4 tV = *(const int4*)(Vtb + base + ((long)row << 11) + jbase + off);
            *(int4*)&sv[row * LDP + off] = tV;
        }
        __syncthreads();

        bf16x8 kf[4][2], vf[4][2];
        #pragma unroll
        for (int ct = 0; ct < 4; ++ct) {
            kf[ct][0] = *(const bf16x8*)&sk[(ct * 16 + l16) * LDP + quad * 8];
            kf[ct][1] = *(const bf16x8*)&sk[(ct * 16 + l16) * LDP + 32 + quad * 8];
            vf[ct][0] = *(const bf16x8*)&sv[(ct * 16 + l16) * LDP + quad * 8];
            vf[ct][1] = *(const bf16x8*)&sv[(ct * 16 + l16) * LDP + 32 + quad * 8];
        }

        short* pw = sp[wave];

        #pragma unroll
        for (int g = 0; g < 2; ++g) {
            if (g == 0 && jt == 2 * t + 1) continue;

            f32x4 s[4];
            #pragma unroll
            for (int ct = 0; ct < 4; ++ct) {
                f32x4 z = (f32x4){0.f, 0.f, 0.f, 0.f};
                z = __builtin_amdgcn_mfma_f32_16x16x32_bf16(kf[ct][0], qf[g][0], z, 0, 0, 0);
                z = __builtin_amdgcn_mfma_f32_16x16x32_bf16(kf[ct][1], qf[g][1], z, 0, 0, 0);
                s[ct] = z;
            }

            const int iq = r0 + 64 * g + wave * 16 + l16;
            if (jt == 2 * t + g) {
                #pragma unroll
                for (int ct = 0; ct < 4; ++ct)
                    #pragma unroll
                    for (int r = 0; r < 4; ++r) {
                        const int j = jbase + ct * 16 + quad * 4 + r;
                        const bool ok = (j < iq) || (iq == 0 && j == 0);
                        if (!ok) s[ct][r] = -INFINITY;
                    }
            }

            float mx = MINIT;
            #pragma unroll
            for (int ct = 0; ct < 4; ++ct)
                #pragma unroll
                for (int r = 0; r < 4; ++r) mx = fmaxf(mx, s[ct][r]);
            mx = fmaxf(mx, __shfl_xor(mx, 16, 64));
            mx = fmaxf(mx, __shfl_xor(mx, 32, 64));
            const float mn = fmaxf(mq[g], mx);
            const float alpha = __expf(mq[g] - mn);
            mq[g] = mn;
            float ss = 0.f;
            #pragma unroll
            for (int ct = 0; ct < 4; ++ct)
                #pragma unroll
                for (int r = 0; r < 4; ++r) {
                    const float e = __expf(s[ct][r] - mn);
                    s[ct][r] = e;
                    ss += e;
                }
            ss += __shfl_xor(ss, 16, 64);
            ss += __shfl_xor(ss, 32, 64);
            lq[g] = lq[g] * alpha + ss;

            #pragma unroll
            for (int ct = 0; ct < 4; ++ct) {
                short4 p4;
                p4.x = f2bf(s[ct][0]); p4.y = f2bf(s[ct][1]);
                p4.z = f2bf(s[ct][2]); p4.w = f2bf(s[ct][3]);
                *(short4*)&pw[l16 * LDP + ct * 16 + quad * 4] = p4;
            }

            #pragma unroll
            for (int ct = 0; ct < 4; ++ct)
                #pragma unroll
                for (int r = 0; r < 4; ++r) acc_o[g][ct][r] *= alpha;

            bf16x8 pf0 = *(const bf16x8*)&pw[l16 * LDP + quad * 8];
            bf16x8 pf1 = *(const bf16x8*)&pw[l16 * LDP + 32 + quad * 8];
            #pragma unroll
            for (int ct = 0; ct < 4; ++ct) {
                acc_o[g][ct] = __builtin_amdgcn_mfma_f32_16x16x32_bf16(
                    vf[ct][0], pf0, acc_o[g][ct], 0, 0, 0);
                acc_o[g][ct] = __builtin_amdgcn_mfma_f32_16x16x32_bf16(
                    vf[ct][1], pf1, acc_o[g][ct], 0, 0, 0);
            }
        }
    }

    #pragma unroll
    for (int g = 0; g < 2; ++g) {
        const float inv = 1.f / lq[g];
        const int iq = r0 + 64 * g + wave * 16 + l16;
        short* orow = ctx + (long)(b * SEQ + iq) * DATTN + h * HD;
        #pragma unroll
        for (int ct = 0; ct < 4; ++ct) {
            short4 o4;
            o4.x = f2bf(acc_o[g][ct][0] * inv);
            o4.y = f2bf(acc_o[g][ct][1] * inv);
            o4.z = f2bf(acc_o[g][ct][2] * inv);
            o4.w = f2bf(acc_o[g][ct][3] * inv);
            *(short4*)&orow[ct * 16 + quad * 4] = o4;
        }
    }
}

extern "C" void kernel_launch(void* const* d_in, const int* in_sizes, int n_in,
                              void* d_out, int out_size, void* d_ws, size_t ws_size,
                              hipStream_t stream) {
    const float* q  = (const float*)d_in[0];
    const float* k  = (const float*)d_in[1];
    const float* v  = (const float*)d_in[2];
    const float* Wq = (const float*)d_in[3];
    const float* Wk = (const float*)d_in[4];
    const float* Wv = (const float*)d_in[5];
    const float* Wo = (const float*)d_in[6];
    float* out = (float*)d_out;

    // workspace (bf16 shorts), 64 MB total:
    // qb|kb|vb (4M each) | wqb|wkb|wvb|wob (1M each) | Qb|Kb|Vtb|ctx (4M each)
    const long QKV = (long)MM * EMB;      // 4,194,304
    const long WSZ = (long)DATTN * EMB;   // 1,048,576
    short* base = (short*)d_ws;
    short* qb  = base;
    short* kb  = qb + QKV;
    short* vb  = kb + QKV;
    short* wqb = vb + QKV;
    short* wkb = wqb + WSZ;
    short* wvb = wkb + WSZ;
    short* wob = wvb + WSZ;
    short* Qb  = wob + WSZ;
    short* Kb  = Qb + QKV;
    short* Vtb = Kb + QKV;
    short* ctx = Vtb + QKV;

    // 1) fp32 -> bf16 pre-convert (16M floats, grid covers exactly)
    cvt_all<<<16384, 256, 0, stream>>>(q, k, v, Wq, Wk, Wv, Wo, qb);

    // 2) fused Q/K/V projection (bf16 MFMA, global_load_lds staging)
    gemm_proj_bf16<<<dim3(MM / 128, DATTN / 128, 3), 256, 0, stream>>>(
        qb, kb, vb, wqb, wkb, wvb, Qb, Kb, Vtb);

    // 3) RoPE on Q and K (fused, grid.y = 2)
    rope_bf16<<<dim3(8192, 2), 256, 0, stream>>>((unsigned short*)Qb, (unsigned short*)Kb);

    // 4) flash attention
    flash_attn_mfma<<<dim3(SEQ / 128, NH, BATCH), 256, 0, stream>>>(Qb, Kb, Vtb, ctx);

    // 5) output GEMM
    gemm_out_bf16<<<dim3(MM / 128, EMB / 128), 256, 0, stream>>>(ctx, wob, out);
}

// Round 11
// 251.244 us; speedup vs baseline: 29.8796x; 1.0554x over previous
//
#include <hip/hip_runtime.h>
#include <hip/hip_bf16.h>

// Problem constants (fixed shapes)
#define BATCH 2
#define SEQ   2048
#define EMB   1024
#define DATTN 1024
#define NH    16
#define HD    64
#define MM    (BATCH*SEQ)        // 4096 rows
#define SCALE 0.03125f           // 1/sqrt(1024), exact power of 2
#define MINIT -1.0e30f
#define ROPE_COEF 0.41524101186f // (2/64)*log2(10000)

using bf16x8 = __attribute__((ext_vector_type(8))) short;   // 8 bf16 (4 VGPRs)
using f32x4  = __attribute__((ext_vector_type(4))) float;   // MFMA C/D

__device__ inline short f2bf(float x) {
    __hip_bfloat16 b = __float2bfloat16(x);
    return *reinterpret_cast<short*>(&b);
}

// async global->LDS, 16 B per lane. LDS dst must be wave-uniform (HW scatters
// lane i to dst + i*16); global src is per-lane. [m03/m97]
__device__ inline void gl_lds16(const short* g, short* l) {
    __builtin_amdgcn_global_load_lds(
        (const __attribute__((address_space(1))) unsigned int*)g,
        (__attribute__((address_space(3))) unsigned int*)l, 16, 0, 0);
}

// ---------------- fp32 -> bf16 pre-convert (q,k,v,Wq,Wk,Wv,Wo) ----------------
__global__ __launch_bounds__(256)
void cvt_all(const float* __restrict__ q, const float* __restrict__ k,
             const float* __restrict__ v,
             const float* __restrict__ Wq, const float* __restrict__ Wk,
             const float* __restrict__ Wv, const float* __restrict__ Wo,
             short* __restrict__ dst)
{
    const long QKV = (long)MM * EMB;      // 4,194,304
    const long WSZ = (long)DATTN * EMB;   // 1,048,576
    const long i = ((long)blockIdx.x * 256 + threadIdx.x) * 4;
    const float* s;
    long off;
    if (i < 3 * QKV) {
        const int seg = (int)(i / QKV);
        off = i - (long)seg * QKV;
        s = (seg == 0) ? q : (seg == 1) ? k : v;
    } else {
        const long j = i - 3 * QKV;
        const int seg = (int)(j / WSZ);
        off = j - (long)seg * WSZ;
        s = (seg == 0) ? Wq : (seg == 1) ? Wk : (seg == 2) ? Wv : Wo;
    }
    float4 x = *(const float4*)(s + off);
    short4 y;
    y.x = f2bf(x.x); y.y = f2bf(x.y); y.z = f2bf(x.z); y.w = f2bf(x.w);
    *(short4*)(dst + i) = y;
}

// ---------------- bf16 MFMA GEMM: 128x128 tile, BK=32, global_load_lds staging ----------------
// stage one 128x32-bf16 tile (8 KB): 2 insts/wave
__device__ inline void stage_tile(const short* g, short* lds, int wave, int lane) {
    #pragma unroll
    for (int qq = 0; qq < 2; ++qq) {
        const int r = wave * 32 + qq * 16 + (lane >> 2);
        gl_lds16(g + (long)r * EMB + (lane & 3) * 8, lds + (wave * 2 + qq) * 512);
    }
}

// Fused Q/K/V projection with RoPE fused into the epilogue for Q/K.
//   z=0: Qb head-layout [B,H,S,HD], pre-scaled by SCALE, RoPE'd
//   z=1: Kb head-layout [B,H,S,HD], RoPE'd
//   z=2: Vtb TRANSPOSED [B,H,HD,S]
__global__ __launch_bounds__(256)
void gemm_proj_bf16(const short* __restrict__ qb, const short* __restrict__ kb,
                    const short* __restrict__ vb,
                    const short* __restrict__ wqb, const short* __restrict__ wkb,
                    const short* __restrict__ wvb,
                    short* __restrict__ Qb, short* __restrict__ Kb,
                    short* __restrict__ Vtb)
{
    const short* A; const short* B;
    if (blockIdx.z == 0)      { A = qb; B = wqb; }
    else if (blockIdx.z == 1) { A = kb; B = wkb; }
    else                      { A = vb; B = wvb; }

    __shared__ short sA[128 * 32];
    __shared__ short sB[128 * 32];

    const int tid  = threadIdx.x;
    const int wave = tid >> 6, lane = tid & 63;
    const int quad = lane >> 4, l16 = lane & 15;
    const int wm = (wave >> 1) * 64, wn = (wave & 1) * 64;
    const long m0 = (long)blockIdx.x * 128, n0 = (long)blockIdx.y * 128;

    f32x4 acc[4][4];
    #pragma unroll
    for (int i = 0; i < 4; ++i)
        #pragma unroll
        for (int j = 0; j < 4; ++j) acc[i][j] = (f32x4){0.f, 0.f, 0.f, 0.f};

    for (int kt = 0; kt < EMB; kt += 32) {
        __syncthreads();
        stage_tile(A + m0 * EMB + kt, sA, wave, lane);
        stage_tile(B + n0 * EMB + kt, sB, wave, lane);
        __syncthreads();

        bf16x8 af[4], bfr[4];
        #pragma unroll
        for (int rt = 0; rt < 4; ++rt)
            af[rt] = *(const bf16x8*)&sA[(wm + rt * 16 + l16) * 32 + quad * 8];
        #pragma unroll
        for (int ct = 0; ct < 4; ++ct)
            bfr[ct] = *(const bf16x8*)&sB[(wn + ct * 16 + l16) * 32 + quad * 8];
        #pragma unroll
        for (int rt = 0; rt < 4; ++rt)
            #pragma unroll
            for (int ct = 0; ct < 4; ++ct)
                acc[rt][ct] = __builtin_amdgcn_mfma_f32_16x16x32_bf16(
                    af[rt], bfr[ct], acc[rt][ct], 0, 0, 0);
    }

    if (blockIdx.z < 2) {
        // Q/K: fused RoPE. Pair (d even, d+1) lives in adjacent l16 lanes ->
        // shfl_xor(.,1) exchanges partners. Rotation applied to fp32 acc
        // before the single bf16 rounding.
        short* C = (blockIdx.z == 0) ? Qb : Kb;
        const float scl = (blockIdx.z == 0) ? SCALE : 1.0f;
        const int odd = l16 & 1;
        #pragma unroll
        for (int ct = 0; ct < 4; ++ct) {
            const long col = n0 + wn + ct * 16 + l16;
            const int hh = (int)(col >> 6), dd = (int)(col & (HD - 1));
            const float invf = exp2f(-ROPE_COEF * (float)(dd >> 1));
            #pragma unroll
            for (int rt = 0; rt < 4; ++rt) {
                #pragma unroll
                for (int reg = 0; reg < 4; ++reg) {
                    const long row = m0 + wm + rt * 16 + quad * 4 + reg;
                    const int bb = (int)(row >> 11), ss = (int)(row & (SEQ - 1));
                    const float val = acc[rt][ct][reg];
                    const float prt = __shfl_xor(val, 1, 64);
                    float sn, cs;
                    __sincosf((float)ss * invf, &sn, &cs);
                    const float o = odd ? (prt * sn + val * cs)
                                        : (val * cs - prt * sn);
                    C[(((long)(bb * NH + hh)) << 17) + ((long)ss << 6) + dd] =
                        f2bf(o * scl);
                }
            }
        }
    } else {
        // V transposed: Vt[((b*NH+h)*HD + d)*SEQ + s]; 4 regs = 4 consecutive s
        #pragma unroll
        for (int rt = 0; rt < 4; ++rt) {
            #pragma unroll
            for (int ct = 0; ct < 4; ++ct) {
                const long row0 = m0 + wm + rt * 16 + quad * 4;
                const long col  = n0 + wn + ct * 16 + l16;
                const int bb = (int)(row0 >> 11), ss = (int)(row0 & (SEQ - 1));
                const int hh = (int)(col >> 6),   dd = (int)(col & (HD - 1));
                short4 s4;
                s4.x = f2bf(acc[rt][ct][0]); s4.y = f2bf(acc[rt][ct][1]);
                s4.z = f2bf(acc[rt][ct][2]); s4.w = f2bf(acc[rt][ct][3]);
                *(short4*)&Vtb[(((long)(bb * NH + hh)) << 17) + ((long)dd << 11) + ss] = s4;
            }
        }
    }
}

// Output GEMM: out = ctx(bf16) @ Wo^T(bf16), out fp32 [4096,1024]
__global__ __launch_bounds__(256)
void gemm_out_bf16(const short* __restrict__ Ab, const short* __restrict__ Bb,
                   float* __restrict__ C)
{
    __shared__ short sA[128 * 32];
    __shared__ short sB[128 * 32];

    const int tid  = threadIdx.x;
    const int wave = tid >> 6, lane = tid & 63;
    const int quad = lane >> 4, l16 = lane & 15;
    const int wm = (wave >> 1) * 64, wn = (wave & 1) * 64;
    const long m0 = (long)blockIdx.x * 128, n0 = (long)blockIdx.y * 128;

    f32x4 acc[4][4];
    #pragma unroll
    for (int i = 0; i < 4; ++i)
        #pragma unroll
        for (int j = 0; j < 4; ++j) acc[i][j] = (f32x4){0.f, 0.f, 0.f, 0.f};

    for (int kt = 0; kt < DATTN; kt += 32) {
        __syncthreads();
        stage_tile(Ab + m0 * DATTN + kt, sA, wave, lane);
        stage_tile(Bb + n0 * DATTN + kt, sB, wave, lane);
        __syncthreads();

        bf16x8 af[4], bfr[4];
        #pragma unroll
        for (int rt = 0; rt < 4; ++rt)
            af[rt] = *(const bf16x8*)&sA[(wm + rt * 16 + l16) * 32 + quad * 8];
        #pragma unroll
        for (int ct = 0; ct < 4; ++ct)
            bfr[ct] = *(const bf16x8*)&sB[(wn + ct * 16 + l16) * 32 + quad * 8];
        #pragma unroll
        for (int rt = 0; rt < 4; ++rt)
            #pragma unroll
            for (int ct = 0; ct < 4; ++ct)
                acc[rt][ct] = __builtin_amdgcn_mfma_f32_16x16x32_bf16(
                    af[rt], bfr[ct], acc[rt][ct], 0, 0, 0);
    }

    #pragma unroll
    for (int rt = 0; rt < 4; ++rt) {
        #pragma unroll
        for (int ct = 0; ct < 4; ++ct) {
            #pragma unroll
            for (int reg = 0; reg < 4; ++reg) {
                const long row = m0 + wm + rt * 16 + quad * 4 + reg;
                const long col = n0 + wn + ct * 16 + l16;
                C[row * EMB + col] = acc[rt][ct][reg];
            }
        }
    }
}

// ---------------- MFMA flash attention (S^T formulation, TJ=128 staging) ----------------
// Block = (b, h, 128-query tile), 4 waves, 2 query groups of 16 per wave.
// Per barrier round stage 128 keys as two 64-key half-tiles (sk2/sv2), then
// process each half with the R9-verified body. Halves barrier rounds vs R10.
#define LDP 72

__global__ __launch_bounds__(256, 1)
void flash_attn_mfma(const short* __restrict__ Qb,
                     const short* __restrict__ Kb,
                     const short* __restrict__ Vtb,
                     short* __restrict__ ctx)
{
    const int t  = (SEQ / 128) - 1 - blockIdx.x;   // heavy tiles first
    const int h  = blockIdx.y, b = blockIdx.z;
    const int tid = threadIdx.x;
    const int wave = tid >> 6, lane = tid & 63;
    const int quad = lane >> 4, l16 = lane & 15;
    const int r0 = t * 128;

    __shared__ short sk2[2][64 * LDP];
    __shared__ short sv2[2][64 * LDP];
    __shared__ short sp[4][16 * LDP];

    const long base = ((long)(b * NH + h)) << 17;   // SEQ*HD = 2^17

    bf16x8 qf[2][2];
    #pragma unroll
    for (int g = 0; g < 2; ++g)
        #pragma unroll
        for (int tt = 0; tt < 2; ++tt)
            qf[g][tt] = *(const bf16x8*)(Qb + base
                + (long)(r0 + 64 * g + wave * 16 + l16) * HD + tt * 32 + quad * 8);

    f32x4 acc_o[2][4];
    #pragma unroll
    for (int g = 0; g < 2; ++g)
        #pragma unroll
        for (int ct = 0; ct < 4; ++ct) acc_o[g][ct] = (f32x4){0.f, 0.f, 0.f, 0.f};
    float mq[2] = {MINIT, MINIT};
    float lq[2] = {0.f, 0.f};

    const int njt = t + 1;     // 128-key tiles

    #pragma unroll 1
    for (int jt = 0; jt < njt; ++jt) {
        const int jbase = jt * 128;

        __syncthreads();   // protect previous-iteration sk2/sv2 reads
        #pragma unroll
        for (int c = 0; c < 4; ++c) {
            int cc   = c * 256 + tid;         // 0..1023
            int half = cc >> 9;               // 0..1
            int row  = (cc >> 3) & 63;        // 0..63
            int off  = (cc & 7) * 8;          // 0..56
            int4 tK = *(const int4*)(Kb + base
                + (long)(jbase + half * 64 + row) * HD + off);
            *(int4*)&sk2[half][row * LDP + off] = tK;
            int4 tV = *(const int4*)(Vtb + base
                + ((long)row << 11) + jbase + half * 64 + off);
            *(int4*)&sv2[half][row * LDP + off] = tV;
        }
        __syncthreads();

        #pragma unroll
        for (int half = 0; half < 2; ++half) {
            const int jb2 = jbase + half * 64;
            const int jt2 = 2 * jt + half;    // 64-key tile index
            const short* skh = sk2[half];
            const short* svh = sv2[half];

            bf16x8 kf[4][2], vf[4][2];
            #pragma unroll
            for (int ct = 0; ct < 4; ++ct) {
                kf[ct][0] = *(const bf16x8*)&skh[(ct * 16 + l16) * LDP + quad * 8];
                kf[ct][1] = *(const bf16x8*)&skh[(ct * 16 + l16) * LDP + 32 + quad * 8];
                vf[ct][0] = *(const bf16x8*)&svh[(ct * 16 + l16) * LDP + quad * 8];
                vf[ct][1] = *(const bf16x8*)&svh[(ct * 16 + l16) * LDP + 32 + quad * 8];
            }

            short* pw = sp[wave];

            #pragma unroll
            for (int g = 0; g < 2; ++g) {
                if (g == 0 && jt2 == 2 * t + 1) continue;   // fully masked

                f32x4 s[4];
                #pragma unroll
                for (int ct = 0; ct < 4; ++ct) {
                    f32x4 z = (f32x4){0.f, 0.f, 0.f, 0.f};
                    z = __builtin_amdgcn_mfma_f32_16x16x32_bf16(kf[ct][0], qf[g][0], z, 0, 0, 0);
                    z = __builtin_amdgcn_mfma_f32_16x16x32_bf16(kf[ct][1], qf[g][1], z, 0, 0, 0);
                    s[ct] = z;
                }

                const int iq = r0 + 64 * g + wave * 16 + l16;
                if (jt2 == 2 * t + g) {   // only tile that can violate j < i
                    #pragma unroll
                    for (int ct = 0; ct < 4; ++ct)
                        #pragma unroll
                        for (int r = 0; r < 4; ++r) {
                            const int j = jb2 + ct * 16 + quad * 4 + r;
                            const bool ok = (j < iq) || (iq == 0 && j == 0);
                            if (!ok) s[ct][r] = -INFINITY;
                        }
                }

                float mx = MINIT;
                #pragma unroll
                for (int ct = 0; ct < 4; ++ct)
                    #pragma unroll
                    for (int r = 0; r < 4; ++r) mx = fmaxf(mx, s[ct][r]);
                mx = fmaxf(mx, __shfl_xor(mx, 16, 64));
                mx = fmaxf(mx, __shfl_xor(mx, 32, 64));
                const float mn = fmaxf(mq[g], mx);
                const float alpha = __expf(mq[g] - mn);
                mq[g] = mn;
                float ss = 0.f;
                #pragma unroll
                for (int ct = 0; ct < 4; ++ct)
                    #pragma unroll
                    for (int r = 0; r < 4; ++r) {
                        const float e = __expf(s[ct][r] - mn);
                        s[ct][r] = e;
                        ss += e;
                    }
                ss += __shfl_xor(ss, 16, 64);
                ss += __shfl_xor(ss, 32, 64);
                lq[g] = lq[g] * alpha + ss;

                #pragma unroll
                for (int ct = 0; ct < 4; ++ct) {
                    short4 p4;
                    p4.x = f2bf(s[ct][0]); p4.y = f2bf(s[ct][1]);
                    p4.z = f2bf(s[ct][2]); p4.w = f2bf(s[ct][3]);
                    *(short4*)&pw[l16 * LDP + ct * 16 + quad * 4] = p4;
                }

                #pragma unroll
                for (int ct = 0; ct < 4; ++ct)
                    #pragma unroll
                    for (int r = 0; r < 4; ++r) acc_o[g][ct][r] *= alpha;

                bf16x8 pf0 = *(const bf16x8*)&pw[l16 * LDP + quad * 8];
                bf16x8 pf1 = *(const bf16x8*)&pw[l16 * LDP + 32 + quad * 8];
                #pragma unroll
                for (int ct = 0; ct < 4; ++ct) {
                    acc_o[g][ct] = __builtin_amdgcn_mfma_f32_16x16x32_bf16(
                        vf[ct][0], pf0, acc_o[g][ct], 0, 0, 0);
                    acc_o[g][ct] = __builtin_amdgcn_mfma_f32_16x16x32_bf16(
                        vf[ct][1], pf1, acc_o[g][ct], 0, 0, 0);
                }
            }
        }
    }

    #pragma unroll
    for (int g = 0; g < 2; ++g) {
        const float inv = 1.f / lq[g];
        const int iq = r0 + 64 * g + wave * 16 + l16;
        short* orow = ctx + (long)(b * SEQ + iq) * DATTN + h * HD;
        #pragma unroll
        for (int ct = 0; ct < 4; ++ct) {
            short4 o4;
            o4.x = f2bf(acc_o[g][ct][0] * inv);
            o4.y = f2bf(acc_o[g][ct][1] * inv);
            o4.z = f2bf(acc_o[g][ct][2] * inv);
            o4.w = f2bf(acc_o[g][ct][3] * inv);
            *(short4*)&orow[ct * 16 + quad * 4] = o4;
        }
    }
}

extern "C" void kernel_launch(void* const* d_in, const int* in_sizes, int n_in,
                              void* d_out, int out_size, void* d_ws, size_t ws_size,
                              hipStream_t stream) {
    const float* q  = (const float*)d_in[0];
    const float* k  = (const float*)d_in[1];
    const float* v  = (const float*)d_in[2];
    const float* Wq = (const float*)d_in[3];
    const float* Wk = (const float*)d_in[4];
    const float* Wv = (const float*)d_in[5];
    const float* Wo = (const float*)d_in[6];
    float* out = (float*)d_out;

    // workspace (bf16 shorts), 64 MB total:
    // qb|kb|vb (4M each) | wqb|wkb|wvb|wob (1M each) | Qb|Kb|Vtb|ctx (4M each)
    const long QKV = (long)MM * EMB;      // 4,194,304
    const long WSZ = (long)DATTN * EMB;   // 1,048,576
    short* base = (short*)d_ws;
    short* qb  = base;
    short* kb  = qb + QKV;
    short* vb  = kb + QKV;
    short* wqb = vb + QKV;
    short* wkb = wqb + WSZ;
    short* wvb = wkb + WSZ;
    short* wob = wvb + WSZ;
    short* Qb  = wob + WSZ;
    short* Kb  = Qb + QKV;
    short* Vtb = Kb + QKV;
    short* ctx = Vtb + QKV;

    // 1) fp32 -> bf16 pre-convert
    cvt_all<<<16384, 256, 0, stream>>>(q, k, v, Wq, Wk, Wv, Wo, qb);

    // 2) fused Q/K/V projection + RoPE (bf16 MFMA, global_load_lds staging)
    gemm_proj_bf16<<<dim3(MM / 128, DATTN / 128, 3), 256, 0, stream>>>(
        qb, kb, vb, wqb, wkb, wvb, Qb, Kb, Vtb);

    // 3) flash attention (TJ=128 staging)
    flash_attn_mfma<<<dim3(SEQ / 128, NH, BATCH), 256, 0, stream>>>(Qb, Kb, Vtb, ctx);

    // 4) output GEMM
    gemm_out_bf16<<<dim3(MM / 128, EMB / 128), 256, 0, stream>>>(ctx, wob, out);
}